// Round 5
// baseline (4169.762 us; speedup 1.0000x reference)
//
#include <hip/hip_runtime.h>
#include <cmath>

typedef unsigned short u16;
typedef short bf16x8 __attribute__((ext_vector_type(8)));
typedef float f32x4 __attribute__((ext_vector_type(4)));

#define S_N 1025
#define W_N 128
#define H_N 200
#define FH_N 800
#define KP 232       // A-staging row stride in u16 (464B)
#define SGP 911      // sG row stride in floats
#define MID 512
#define NT 56        // padded n-tile count (50 real + 6 zero)
#define PKT (NT * 7 * 512)   // packed elems per weight matrix = 200704

__device__ __forceinline__ float bf2f(u16 u) {
  unsigned int x = ((unsigned int)u) << 16;
  return __builtin_bit_cast(float, x);
}
__device__ __forceinline__ u16 f2bf(float f) {
  unsigned int x = __builtin_bit_cast(unsigned int, f);
  x += 0x7fffu + ((x >> 16) & 1u);
  return (u16)(x >> 16);
}
#define LOG2E 1.44269504088896f
__device__ __forceinline__ float fsigm(float x) {
  float e = __builtin_amdgcn_exp2f(-fabsf(x) * LOG2E);
  float p = __builtin_amdgcn_rcpf(1.f + e);
  return x >= 0.f ? p : 1.f - p;
}
__device__ __forceinline__ float ftanh(float x) {
  float e = __builtin_amdgcn_exp2f(-2.f * fabsf(x) * LOG2E);
  float th = (1.f - e) * __builtin_amdgcn_rcpf(1.f + e);
  return x >= 0.f ? th : -th;
}

__device__ __forceinline__ const bf16x8* pkptr(const u16* pk, int tt, int kcc, int lane) {
  return (const bf16x8*)(pk + (size_t)((tt * 7 + kcc) * 512 + lane * 8));
}

// ---------------------------------------------------------------------------
// Kernel 0: repack 8 fp32 weight matrices into bf16 MFMA-B-fragment order.
// dst: [wih_ctx|whh_ctx|wih_tgt|whh_tgt|whh_prev|whh_post|wih_prev|wih_post]
// ---------------------------------------------------------------------------
__global__ __launch_bounds__(256) void k_w2b(
    const float* __restrict__ p0, const float* __restrict__ p1,
    const float* __restrict__ p2, const float* __restrict__ p3,
    const float* __restrict__ p4, const float* __restrict__ p5,
    const float* __restrict__ p6, const float* __restrict__ p7,
    u16* __restrict__ dst)
{
  int i = blockIdx.x * 256 + threadIdx.x;
  if (i >= 8 * PKT) return;
  int w = i / PKT, r = i - w * PKT;
  int tt = r / 3584;
  int q = r - tt * 3584;
  int kcc = q >> 9;
  int lane = (q >> 3) & 63;
  int j = q & 7;
  int col = lane & 15, quad = lane >> 4;
  int gate = tt * 16 + col;
  int k = kcc * 32 + quad * 8 + j;
  const float* ps[8] = {p0, p1, p2, p3, p4, p5, p6, p7};
  u16 v = 0;
  if (gate < FH_N && k < H_N) v = f2bf(ps[w][(size_t)gate * H_N + k]);
  dst[i] = v;
}

// ---------------------------------------------------------------------------
// Kernel 0b: bitonic sort of sentence ids by length (descending) -> order[].
// ---------------------------------------------------------------------------
__global__ __launch_bounds__(1024) void k_sort(
    const int* __restrict__ lengths, int* __restrict__ order)
{
  __shared__ int key[2048], val[2048];
  int tid = threadIdx.x;
  for (int v = 0; v < 2; ++v) {
    int i = tid + v * 1024;
    key[i] = (i < S_N) ? lengths[i] : -1;
    val[i] = (i < S_N) ? i : (S_N - 1);
  }
  __syncthreads();
  for (int k = 2; k <= 2048; k <<= 1)
    for (int j = k >> 1; j > 0; j >>= 1) {
      for (int v = 0; v < 2; ++v) {
        int i = tid + v * 1024;
        int ix = i ^ j;
        if (ix > i) {
          bool descRegion = ((i & k) == 0);
          int ki = key[i], kx = key[ix];
          if ((ki < kx) == descRegion) {
            key[i] = kx; key[ix] = ki;
            int tv = val[i]; val[i] = val[ix]; val[ix] = tv;
          }
        }
      }
      __syncthreads();
    }
  for (int v = 0; v < 2; ++v) {
    int i = tid + v * 1024;
    if (i < S_N) order[i] = val[i];
  }
}

// ---------------------------------------------------------------------------
// Kernel G: word-level input projection GEMM (parallel over all (s,t)).
// gxw[s][t][gate] = words[s][t] @ wih^T + (bih+bhh); s==MID uses tgt weights.
// Block = (sentence, t-half of 64); computes only t-tiles < lengths[s].
// ---------------------------------------------------------------------------
__global__ __launch_bounds__(512, 2) void k_gxw(
    const float* __restrict__ words, const int* __restrict__ lengths,
    const u16* __restrict__ wihb_ctx, const float* __restrict__ bih_ctx, const float* __restrict__ bhh_ctx,
    const u16* __restrict__ wihb_tgt, const float* __restrict__ bih_tgt, const float* __restrict__ bhh_tgt,
    float* __restrict__ gxw)
{
  const int b = blockIdx.x;
  const int s = b >> 1;
  const int t0 = (b & 1) * 64;
  const int len = lengths[s];
  const int nt = min(4, (len - t0 + 15) >> 4);
  if (nt <= 0) return;
  const bool tg = (s == MID);
  const u16* wih = tg ? wihb_tgt : wihb_ctx;
  const float* bih = tg ? bih_tgt : bih_ctx;
  const float* bhh = tg ? bhh_tgt : bhh_ctx;

  __shared__ __align__(16) u16 sWhi[64 * KP];
  __shared__ __align__(16) u16 sWlo[64 * KP];
  __shared__ float sB[FH_N];
  const int tid = threadIdx.x;
  for (int e = tid; e < 64 * KP; e += 512) { sWhi[e] = 0; sWlo[e] = 0; }
  for (int e = tid; e < FH_N; e += 512) sB[e] = bih[e] + bhh[e];
  __syncthreads();
  const int rows = nt * 16;
  for (int e = tid; e < rows * H_N; e += 512) {
    int rr = e / H_N, k = e - rr * H_N;
    float v = words[((size_t)s * W_N + t0 + rr) * H_N + k];
    u16 vh = f2bf(v);
    sWhi[rr * KP + k] = vh;
    sWlo[rr * KP + k] = f2bf(v - bf2f(vh));
  }
  __syncthreads();

  const int lane = tid & 63, wv = tid >> 6, quad = lane >> 4, col = lane & 15;
  f32x4 acc[4][7];
#pragma unroll
  for (int jt = 0; jt < 4; ++jt)
#pragma unroll
    for (int i = 0; i < 7; ++i) { f32x4 z = {0.f, 0.f, 0.f, 0.f}; acc[jt][i] = z; }

  bf16x8 Bw[2][7];
#pragma unroll
  for (int i = 0; i < 7; ++i) Bw[0][i] = *pkptr(wih, wv + 8 * i, 0, lane);
#pragma unroll
  for (int kcc = 0; kcc < 7; ++kcc) {
    const int cur = kcc & 1, nxt = cur ^ 1;
    if (kcc < 6) {
#pragma unroll
      for (int i = 0; i < 7; ++i) Bw[nxt][i] = *pkptr(wih, wv + 8 * i, kcc + 1, lane);
    }
#pragma unroll
    for (int jt = 0; jt < 4; ++jt) {
      if (jt < nt) {
        bf16x8 ah = *(const bf16x8*)(sWhi + (jt * 16 + col) * KP + quad * 8 + kcc * 32);
        bf16x8 al = *(const bf16x8*)(sWlo + (jt * 16 + col) * KP + quad * 8 + kcc * 32);
#pragma unroll
        for (int i = 0; i < 7; ++i) {
          acc[jt][i] = __builtin_amdgcn_mfma_f32_16x16x32_bf16(ah, Bw[cur][i], acc[jt][i], 0, 0, 0);
          acc[jt][i] = __builtin_amdgcn_mfma_f32_16x16x32_bf16(al, Bw[cur][i], acc[jt][i], 0, 0, 0);
        }
      }
    }
  }

#pragma unroll
  for (int jt = 0; jt < 4; ++jt) {
    if (jt < nt) {
#pragma unroll
      for (int i = 0; i < 7; ++i) {
        int tt = wv + 8 * i;
        if (tt < 50) {
          float bias = sB[tt * 16 + col];
#pragma unroll
          for (int r = 0; r < 4; ++r) {
            int t = t0 + jt * 16 + quad * 4 + r;
            gxw[((size_t)s * W_N + t) * FH_N + tt * 16 + col] = acc[jt][i][r] + bias;
          }
        }
      }
    }
  }
}

// ---------------------------------------------------------------------------
// Kernel 1 (gx path): word-level recurrent loop. Only whh streamed (401KB/step);
// acc initialized from precomputed gxw (bias baked in), prefetched 1 step ahead.
// ---------------------------------------------------------------------------
__global__ __launch_bounds__(512, 2) void k_word_g(
    const int* __restrict__ lengths, const int* __restrict__ order,
    const float* __restrict__ h0w, const float* __restrict__ c0w,
    const u16* __restrict__ whhb_ctx, const u16* __restrict__ whhb_tgt,
    const float* __restrict__ gxw, float* __restrict__ emb)
{
  const int tid = threadIdx.x;
  const int b = blockIdx.x;
  const bool is_tgt = (b == 65);
  const u16* whh = is_tgt ? whhb_tgt : whhb_ctx;

  __shared__ __align__(16) u16 sHi[16 * KP];
  __shared__ __align__(16) u16 sLo[16 * KP];
  __shared__ float sG[8 * SGP];
  __shared__ int sLen[16], sId[16];

  for (int e = tid; e < 16 * KP; e += 512) { sHi[e] = 0; sLo[e] = 0; }
  if (tid < 16) {
    int slot = b * 16 + tid;
    int s = is_tgt ? MID : order[min(slot, S_N - 1)];
    sId[tid] = s;
    sLen[tid] = lengths[s];
  }
  __syncthreads();

  float creg[7];
#pragma unroll
  for (int r = 0; r < 7; ++r) {
    int e = tid + 512 * r;
    if (e < 16 * H_N) {
      int m = e / H_N, j = e - m * H_N;
      int s = sId[m];
      float h = h0w[(size_t)s * H_N + j];
      u16 hh = f2bf(h);
      sHi[m * KP + j] = hh;
      sLo[m * KP + j] = f2bf(h - bf2f(hh));
      creg[r] = c0w[(size_t)s * H_N + j];
    }
  }
  __syncthreads();
  int Lmax = 1;
  for (int m = 0; m < 16; ++m) Lmax = max(Lmax, sLen[m]);

  const int lane = tid & 63;
  const int wv = tid >> 6;
  const int quad = lane >> 4;
  const int col = lane & 15;
  const int hpass = quad >> 1;

  const u16* aHh = sHi + col * KP + quad * 8;
  const u16* aHl = sLo + col * KP + quad * 8;

  // gx base offsets for this lane's 4 D-rows (sentences quad*4+r)
  int base_r[4];
#pragma unroll
  for (int r = 0; r < 4; ++r) base_r[r] = sId[quad * 4 + r] * (W_N * FH_N) + col;

  // prefetch gx for t=0
  float xc[7][4];
#pragma unroll
  for (int i = 0; i < 7; ++i) {
    int tt = wv + 8 * i;
#pragma unroll
    for (int r = 0; r < 4; ++r)
      xc[i][r] = (tt < 50) ? gxw[(size_t)(base_r[r] + tt * 16)] : 0.f;
  }

#pragma unroll 1
  for (int t = 0; t < Lmax; ++t) {
    f32x4 acc[7];
#pragma unroll
    for (int i = 0; i < 7; ++i) {
      f32x4 z;
#pragma unroll
      for (int r = 0; r < 4; ++r) z[r] = xc[i][r];
      acc[i] = z;
    }
    // prefetch gx for t+1 (consumed next iter; hidden behind MFMA phase)
    if (t + 1 < Lmax) {
#pragma unroll
      for (int i = 0; i < 7; ++i) {
        int tt = wv + 8 * i;
        if (tt < 50) {
#pragma unroll
          for (int r = 0; r < 4; ++r)
            xc[i][r] = gxw[(size_t)(base_r[r] + (t + 1) * FH_N + tt * 16)];
        }
      }
    }

    bf16x8 Bh[2][7];
#pragma unroll
    for (int i = 0; i < 7; ++i) Bh[0][i] = *pkptr(whh, wv + 8 * i, 0, lane);
#pragma unroll
    for (int kcc = 0; kcc < 7; ++kcc) {
      const int cur = kcc & 1, nxt = cur ^ 1;
      if (kcc < 6) {
#pragma unroll
        for (int i = 0; i < 7; ++i) Bh[nxt][i] = *pkptr(whh, wv + 8 * i, kcc + 1, lane);
      }
      bf16x8 ahh = *(const bf16x8*)(aHh + kcc * 32);
      bf16x8 ahl = *(const bf16x8*)(aHl + kcc * 32);
#pragma unroll
      for (int i = 0; i < 7; ++i) {
        acc[i] = __builtin_amdgcn_mfma_f32_16x16x32_bf16(ahh, Bh[cur][i], acc[i], 0, 0, 0);
        acc[i] = __builtin_amdgcn_mfma_f32_16x16x32_bf16(ahl, Bh[cur][i], acc[i], 0, 0, 0);
      }
    }

    // epilogue: two passes of 8 sentence-rows through sG (bias baked into gx)
#pragma unroll 1
    for (int h = 0; h < 2; ++h) {
      if (hpass == h) {
#pragma unroll
        for (int i = 0; i < 7; ++i) {
          int tt = wv + 8 * i;
#pragma unroll
          for (int r = 0; r < 4; ++r)
            sG[((quad & 1) * 4 + r) * SGP + tt * 16 + col] = acc[i][r];
        }
      }
      __syncthreads();
#pragma unroll
      for (int rr = 0; rr < 7; ++rr) {
        int e = tid + 512 * rr;
        if (e < 16 * H_N) {
          int m = e / H_N, j = e - m * H_N;
          if ((m >> 3) == h) {
            const float* gRow = sG + (m - 8 * h) * SGP;
            float ig = gRow[j];
            float fg = gRow[H_N + j];
            float gg = gRow[2 * H_N + j];
            float og = gRow[3 * H_N + j];
            float nc = fsigm(fg) * creg[rr] + fsigm(ig) * ftanh(gg);
            float nh = fsigm(og) * ftanh(nc);
            creg[rr] = nc;
            u16 hh = f2bf(nh);
            sHi[m * KP + j] = hh;
            sLo[m * KP + j] = f2bf(nh - bf2f(hh));
            if (t == sLen[m] - 1) {
              int s = sId[m];
              if (is_tgt) {
                if (m == 0) emb[(size_t)MID * H_N + j] = nh;
              } else if (s != MID) {
                emb[(size_t)s * H_N + j] = nh;
              }
            }
          }
        }
      }
      __syncthreads();
    }
  }
}

// ---------------------------------------------------------------------------
// Kernel 1 (fallback, small ws): round-4 streaming k_word, fixed launch bounds.
// ---------------------------------------------------------------------------
__global__ __launch_bounds__(512, 2) void k_word_s(
    const float* __restrict__ words, const int* __restrict__ lengths,
    const int* __restrict__ order,
    const float* __restrict__ h0w, const float* __restrict__ c0w,
    const u16* __restrict__ wihb_ctx, const u16* __restrict__ whhb_ctx,
    const float* __restrict__ bih_ctx, const float* __restrict__ bhh_ctx,
    const u16* __restrict__ wihb_tgt, const u16* __restrict__ whhb_tgt,
    const float* __restrict__ bih_tgt, const float* __restrict__ bhh_tgt,
    float* __restrict__ emb)
{
  const int tid = threadIdx.x;
  const int b = blockIdx.x;
  const bool is_tgt = (b == 65);
  const u16* wih = is_tgt ? wihb_tgt : wihb_ctx;
  const u16* whh = is_tgt ? whhb_tgt : whhb_ctx;
  const float* bih = is_tgt ? bih_tgt : bih_ctx;
  const float* bhh = is_tgt ? bhh_tgt : bhh_ctx;

  __shared__ __align__(16) u16 sXhi[16 * KP];
  __shared__ __align__(16) u16 sXlo[16 * KP];
  __shared__ __align__(16) u16 sHi[16 * KP];
  __shared__ __align__(16) u16 sLo[16 * KP];
  __shared__ float sG[8 * SGP];
  __shared__ float sB[4 * H_N];
  __shared__ int sLen[16], sId[16];

  for (int e = tid; e < 16 * KP; e += 512) {
    sXhi[e] = 0; sXlo[e] = 0; sHi[e] = 0; sLo[e] = 0;
  }
  if (tid < 16) {
    int slot = b * 16 + tid;
    int s = is_tgt ? MID : order[min(slot, S_N - 1)];
    sId[tid] = s;
    sLen[tid] = lengths[s];
  }
  for (int e = tid; e < 4 * H_N; e += 512) sB[e] = bih[e] + bhh[e];
  __syncthreads();

  float creg[7];
  int offs[7];
#pragma unroll
  for (int r = 0; r < 7; ++r) {
    int e = tid + 512 * r;
    offs[r] = 0;
    if (e < 16 * H_N) {
      int m = e / H_N, j = e - m * H_N;
      int s = sId[m];
      offs[r] = s * (W_N * H_N) + j;
      float h = h0w[(size_t)s * H_N + j];
      u16 hh = f2bf(h);
      sHi[m * KP + j] = hh;
      sLo[m * KP + j] = f2bf(h - bf2f(hh));
      creg[r] = c0w[(size_t)s * H_N + j];
    }
  }
  __syncthreads();
  int Lmax = 1;
  for (int m = 0; m < 16; ++m) Lmax = max(Lmax, sLen[m]);

  const int lane = tid & 63;
  const int wv = tid >> 6;
  const int quad = lane >> 4;
  const int col = lane & 15;
  const int hpass = quad >> 1;

  const u16* aXh = sXhi + col * KP + quad * 8;
  const u16* aXl = sXlo + col * KP + quad * 8;
  const u16* aHh = sHi  + col * KP + quad * 8;
  const u16* aHl = sLo  + col * KP + quad * 8;

  float xreg[7];
#pragma unroll
  for (int r = 0; r < 7; ++r) {
    int e = tid + 512 * r;
    if (e < 16 * H_N) xreg[r] = words[(size_t)offs[r]];
  }

#pragma unroll 1
  for (int t = 0; t < Lmax; ++t) {
#pragma unroll
    for (int r = 0; r < 7; ++r) {
      int e = tid + 512 * r;
      if (e < 16 * H_N) {
        int m = e / H_N, k = e - m * H_N;
        float v = xreg[r];
        u16 vh = f2bf(v);
        sXhi[m * KP + k] = vh;
        sXlo[m * KP + k] = f2bf(v - bf2f(vh));
      }
    }
    __syncthreads();
    if (t + 1 < Lmax) {
#pragma unroll
      for (int r = 0; r < 7; ++r) {
        int e = tid + 512 * r;
        if (e < 16 * H_N) xreg[r] = words[(size_t)offs[r] + (t + 1) * H_N];
      }
    }

    f32x4 acc[7];
#pragma unroll
    for (int i = 0; i < 7; ++i) { f32x4 z4 = {0.f, 0.f, 0.f, 0.f}; acc[i] = z4; }

    bf16x8 Bw[2][7], Bh[2][7];
#pragma unroll
    for (int i = 0; i < 7; ++i) {
      Bw[0][i] = *pkptr(wih, wv + 8 * i, 0, lane);
      Bh[0][i] = *pkptr(whh, wv + 8 * i, 0, lane);
    }
#pragma unroll
    for (int kcc = 0; kcc < 7; ++kcc) {
      const int cur = kcc & 1, nxt = cur ^ 1;
      if (kcc < 6) {
#pragma unroll
        for (int i = 0; i < 7; ++i) {
          Bw[nxt][i] = *pkptr(wih, wv + 8 * i, kcc + 1, lane);
          Bh[nxt][i] = *pkptr(whh, wv + 8 * i, kcc + 1, lane);
        }
      }
      bf16x8 axh = *(const bf16x8*)(aXh + kcc * 32);
      bf16x8 axl = *(const bf16x8*)(aXl + kcc * 32);
      bf16x8 ahh = *(const bf16x8*)(aHh + kcc * 32);
      bf16x8 ahl = *(const bf16x8*)(aHl + kcc * 32);
#pragma unroll
      for (int i = 0; i < 7; ++i) {
        acc[i] = __builtin_amdgcn_mfma_f32_16x16x32_bf16(axh, Bw[cur][i], acc[i], 0, 0, 0);
        acc[i] = __builtin_amdgcn_mfma_f32_16x16x32_bf16(axl, Bw[cur][i], acc[i], 0, 0, 0);
        acc[i] = __builtin_amdgcn_mfma_f32_16x16x32_bf16(ahh, Bh[cur][i], acc[i], 0, 0, 0);
        acc[i] = __builtin_amdgcn_mfma_f32_16x16x32_bf16(ahl, Bh[cur][i], acc[i], 0, 0, 0);
      }
    }

#pragma unroll 1
    for (int h = 0; h < 2; ++h) {
      if (hpass == h) {
#pragma unroll
        for (int i = 0; i < 7; ++i) {
          int tt = wv + 8 * i;
#pragma unroll
          for (int r = 0; r < 4; ++r)
            sG[((quad & 1) * 4 + r) * SGP + tt * 16 + col] = acc[i][r];
        }
      }
      __syncthreads();
#pragma unroll
      for (int rr = 0; rr < 7; ++rr) {
        int e = tid + 512 * rr;
        if (e < 16 * H_N) {
          int m = e / H_N, j = e - m * H_N;
          if ((m >> 3) == h) {
            const float* gRow = sG + (m - 8 * h) * SGP;
            float ig = gRow[j] + sB[j];
            float fg = gRow[H_N + j] + sB[H_N + j];
            float gg = gRow[2 * H_N + j] + sB[2 * H_N + j];
            float og = gRow[3 * H_N + j] + sB[3 * H_N + j];
            float nc = fsigm(fg) * creg[rr] + fsigm(ig) * ftanh(gg);
            float nh = fsigm(og) * ftanh(nc);
            creg[rr] = nc;
            u16 hh = f2bf(nh);
            sHi[m * KP + j] = hh;
            sLo[m * KP + j] = f2bf(nh - bf2f(hh));
            if (t == sLen[m] - 1) {
              int s = sId[m];
              if (is_tgt) {
                if (m == 0) emb[(size_t)MID * H_N + j] = nh;
              } else if (s != MID) {
                emb[(size_t)s * H_N + j] = nh;
              }
            }
          }
        }
      }
      __syncthreads();
    }
  }
}

// ---------------------------------------------------------------------------
// Kernel 2: gx projections for prev/post via MFMA (packed wih).
// ---------------------------------------------------------------------------
__global__ __launch_bounds__(512) void k_gx(
    const float* __restrict__ emb,
    const u16* __restrict__ wihb_prev, const float* __restrict__ bih_prev, const float* __restrict__ bhh_prev,
    const u16* __restrict__ wihb_post, const float* __restrict__ bih_post, const float* __restrict__ bhh_post,
    float* __restrict__ gxp, float* __restrict__ gxq)
{
  const int tid = threadIdx.x;
  const int b = blockIdx.x;
  const bool post = (b >= 33);
  const int t0 = (post ? b - 33 : b) * 16;
  const u16* wih = post ? wihb_post : wihb_prev;
  const float* bih = post ? bih_post : bih_prev;
  const float* bhh = post ? bhh_post : bhh_prev;
  float* out = post ? gxq : gxp;

  __shared__ __align__(16) u16 sEhi[16 * KP];
  __shared__ __align__(16) u16 sElo[16 * KP];
  for (int e = tid; e < 16 * KP; e += 512) { sEhi[e] = 0; sElo[e] = 0; }
  __syncthreads();
  for (int e = tid; e < 16 * H_N; e += 512) {
    int m = e / H_N, k = e - m * H_N;
    int t = t0 + m;
    if (t <= 512) {
      int src = post ? (1024 - t) : t;
      float v = emb[(size_t)src * H_N + k];
      u16 vh = f2bf(v);
      sEhi[m * KP + k] = vh;
      sElo[m * KP + k] = f2bf(v - bf2f(vh));
    }
  }
  __syncthreads();

  const int lane = tid & 63;
  const int wv = tid >> 6;
  const int quad = lane >> 4;
  const int col = lane & 15;
  const u16* aH = sEhi + col * KP + quad * 8;
  const u16* aL = sElo + col * KP + quad * 8;

  bf16x8 Ah[7], Al[7];
#pragma unroll
  for (int kcc = 0; kcc < 7; ++kcc) {
    Ah[kcc] = *(const bf16x8*)(aH + kcc * 32);
    Al[kcc] = *(const bf16x8*)(aL + kcc * 32);
  }

#pragma unroll 1
  for (int i = 0; i < 7; ++i) {
    int tt = wv + 8 * i;
    if (tt >= 50) break;
    int gate = tt * 16 + col;
    f32x4 acc = {0.f, 0.f, 0.f, 0.f};
#pragma unroll
    for (int kcc = 0; kcc < 7; ++kcc) {
      bf16x8 bw = *pkptr(wih, tt, kcc, lane);
      acc = __builtin_amdgcn_mfma_f32_16x16x32_bf16(Ah[kcc], bw, acc, 0, 0, 0);
      acc = __builtin_amdgcn_mfma_f32_16x16x32_bf16(Al[kcc], bw, acc, 0, 0, 0);
    }
    float bias = bih[gate] + bhh[gate];
#pragma unroll
    for (int r = 0; r < 4; ++r) {
      int t = t0 + quad * 4 + r;
      if (t <= 512) out[(size_t)t * FH_N + gate] = acc[r] + bias;
    }
  }
}

// ---------------------------------------------------------------------------
// Kernel 3: prev (block 0) / post (block 1) sentence LSTMs. 513 serial steps.
// (512,2) so afr[7][7] (196 VGPR) stays register-resident — no spill.
// gx prefetched one step ahead.
// ---------------------------------------------------------------------------
__global__ __launch_bounds__(512, 2) void k_sent(
    const u16* __restrict__ whhb_prev, const u16* __restrict__ whhb_post,
    const float* __restrict__ h0p, const float* __restrict__ c0p,
    const float* __restrict__ h0q, const float* __restrict__ c0q,
    const float* __restrict__ gxp, const float* __restrict__ gxq,
    float* __restrict__ outp, float* __restrict__ outq)
{
  const int tid = threadIdx.x;
  const bool post = (blockIdx.x != 0);
  const u16* whh = post ? whhb_post : whhb_prev;
  const float* h0 = post ? h0q : h0p;
  const float* c0 = post ? c0q : c0p;
  const float* gx = post ? gxq : gxp;
  float* outv = post ? outq : outp;

  __shared__ __align__(16) u16 sHi[224];
  __shared__ __align__(16) u16 sLo[224];
  __shared__ float sGa[FH_N];
  __shared__ float sGb[FH_N];

  const int lane = tid & 63;
  const int wv = tid >> 6;
  const int quad = lane >> 4;
  const int col = lane & 15;

  bf16x8 afr[7][7];
#pragma unroll
  for (int i = 0; i < 7; ++i) {
    int tt = wv + 8 * i;
#pragma unroll
    for (int kcc = 0; kcc < 7; ++kcc)
      afr[i][kcc] = *pkptr(whh, tt, kcc, lane);
  }

  if (tid < 224) { sHi[tid] = 0; sLo[tid] = 0; }
  float c = 0.f, last_h = 0.f;
  if (tid < H_N) {
    float h = h0[tid];
    u16 hh = f2bf(h);
    sHi[tid] = hh;
    sLo[tid] = f2bf(h - bf2f(hh));
    c = c0[tid];
  }
  __syncthreads();

  const u16* hb = ((lane & 8) ? sLo : sHi) + quad * 8;
  const bool wrA = (col == 0), wrB = (col == 8);

  float gc0 = 0.f, gc1 = 0.f, gc2 = 0.f, gc3 = 0.f;
  if (tid < H_N) {
    gc0 = gx[tid]; gc1 = gx[H_N + tid]; gc2 = gx[2 * H_N + tid]; gc3 = gx[3 * H_N + tid];
  }

#pragma unroll 1
  for (int t = 0; t < 513; ++t) {
    bf16x8 bfr[7];
#pragma unroll
    for (int kcc = 0; kcc < 7; ++kcc) bfr[kcc] = *(const bf16x8*)(hb + kcc * 32);

    // prefetch next step's gx behind the MFMA phase
    float gn0 = 0.f, gn1 = 0.f, gn2 = 0.f, gn3 = 0.f;
    if (t + 1 < 513 && tid < H_N) {
      const float* g = gx + (size_t)(t + 1) * FH_N;
      gn0 = g[tid]; gn1 = g[H_N + tid]; gn2 = g[2 * H_N + tid]; gn3 = g[3 * H_N + tid];
    }

#pragma unroll
    for (int i = 0; i < 7; ++i) {
      int tt = wv + 8 * i;
      f32x4 acc = {0.f, 0.f, 0.f, 0.f};
#pragma unroll
      for (int kcc = 0; kcc < 7; ++kcc)
        acc = __builtin_amdgcn_mfma_f32_16x16x32_bf16(afr[i][kcc], bfr[kcc], acc, 0, 0, 0);
      if (tt < 50) {
        if (wrA) {
#pragma unroll
          for (int r = 0; r < 4; ++r) sGa[tt * 16 + quad * 4 + r] = acc[r];
        } else if (wrB) {
#pragma unroll
          for (int r = 0; r < 4; ++r) sGb[tt * 16 + quad * 4 + r] = acc[r];
        }
      }
    }
    __syncthreads();

    if (tid < H_N) {
      float ig = sGa[tid] + sGb[tid] + gc0;
      float fg = sGa[H_N + tid] + sGb[H_N + tid] + gc1;
      float gg = sGa[2 * H_N + tid] + sGb[2 * H_N + tid] + gc2;
      float og = sGa[3 * H_N + tid] + sGb[3 * H_N + tid] + gc3;
      float nc = fsigm(fg) * c + fsigm(ig) * ftanh(gg);
      float nh = fsigm(og) * ftanh(nc);
      c = nc;
      last_h = nh;
      u16 hh = f2bf(nh);
      sHi[tid] = hh;
      sLo[tid] = f2bf(nh - bf2f(hh));
    }
    gc0 = gn0; gc1 = gn1; gc2 = gn2; gc3 = gn3;
    __syncthreads();
  }
  if (tid < H_N) outv[tid] = last_h;
}

// ---------------------------------------------------------------------------
// Kernel 4: out = [prev_out ; post_out] @ fc_w^T + fc_b  (fp32 exact)
// ---------------------------------------------------------------------------
__global__ __launch_bounds__(256) void k_fc(
    const float* __restrict__ pout, const float* __restrict__ qout,
    const float* __restrict__ fc_w, const float* __restrict__ fc_b,
    float* __restrict__ out)
{
  const int tid = threadIdx.x;
  if (tid < H_N) {
    float d = fc_b[tid];
    const float* wr = fc_w + (size_t)tid * 2 * H_N;
    for (int k = 0; k < H_N; ++k) d += pout[k] * wr[k];
    for (int k = 0; k < H_N; ++k) d += qout[k] * wr[H_N + k];
    out[tid] = d;
  }
}

extern "C" void kernel_launch(void* const* d_in, const int* in_sizes, int n_in,
                              void* d_out, int out_size, void* d_ws, size_t ws_size,
                              hipStream_t stream) {
  const float* words   = (const float*)d_in[0];
  const int*   lengths = (const int*)d_in[1];
  const float* h0w = (const float*)d_in[2];
  const float* c0w = (const float*)d_in[3];
  const float* h0p = (const float*)d_in[4];
  const float* c0p = (const float*)d_in[5];
  const float* h0q = (const float*)d_in[6];
  const float* c0q = (const float*)d_in[7];
  const float* wih_ctx = (const float*)d_in[8];
  const float* whh_ctx = (const float*)d_in[9];
  const float* bih_ctx = (const float*)d_in[10];
  const float* bhh_ctx = (const float*)d_in[11];
  const float* wih_tgt = (const float*)d_in[12];
  const float* whh_tgt = (const float*)d_in[13];
  const float* bih_tgt = (const float*)d_in[14];
  const float* bhh_tgt = (const float*)d_in[15];
  const float* wih_prev = (const float*)d_in[16];
  const float* whh_prev = (const float*)d_in[17];
  const float* bih_prev = (const float*)d_in[18];
  const float* bhh_prev = (const float*)d_in[19];
  const float* wih_post = (const float*)d_in[20];
  const float* whh_post = (const float*)d_in[21];
  const float* bih_post = (const float*)d_in[22];
  const float* bhh_post = (const float*)d_in[23];
  const float* fc_w = (const float*)d_in[24];
  const float* fc_b = (const float*)d_in[25];
  (void)in_sizes; (void)n_in; (void)out_size;

  float* ws = (float*)d_ws;

  // big layout (with gxw)
  const size_t GXW = (size_t)S_N * W_N * FH_N;   // 104,960,000 floats
  float* b_gxw = ws;
  float* b_emb = ws + GXW;
  float* b_gxp = b_emb + 205000;
  float* b_gxq = b_gxp + 410400;
  float* b_po  = b_gxq + 410400;
  float* b_qo  = b_po + 200;
  int*   b_order = (int*)(b_qo + 200);
  u16*   b_wb  = (u16*)(b_order + 1056);
  size_t need_big = (size_t)((char*)(b_wb + 8 * PKT) - (char*)ws);

  // small layout (round-4 style)
  float* s_emb = ws;
  float* s_gxp = ws + 205000;
  float* s_gxq = ws + 615400;
  float* s_po  = ws + 1025800;
  float* s_qo  = ws + 1026000;
  int*   s_order = (int*)(ws + 1026200);
  u16*   s_wb  = (u16*)(ws + 1027232);

  const bool big = (ws_size >= need_big);
  float* emb = big ? b_emb : s_emb;
  float* gxp = big ? b_gxp : s_gxp;
  float* gxq = big ? b_gxq : s_gxq;
  float* po  = big ? b_po  : s_po;
  float* qo  = big ? b_qo  : s_qo;
  int* order = big ? b_order : s_order;
  u16* wb    = big ? b_wb  : s_wb;

  u16* wihb_ctx  = wb;
  u16* whhb_ctx  = wb + PKT;
  u16* wihb_tgt  = wb + 2 * PKT;
  u16* whhb_tgt  = wb + 3 * PKT;
  u16* whhb_prev = wb + 4 * PKT;
  u16* whhb_post = wb + 5 * PKT;
  u16* wihb_prev = wb + 6 * PKT;
  u16* wihb_post = wb + 7 * PKT;

  k_w2b<<<(8 * PKT + 255) / 256, 256, 0, stream>>>(
      wih_ctx, whh_ctx, wih_tgt, whh_tgt, whh_prev, whh_post,
      wih_prev, wih_post, wb);
  k_sort<<<1, 1024, 0, stream>>>(lengths, order);

  if (big) {
    k_gxw<<<S_N * 2, 512, 0, stream>>>(words, lengths,
                                       wihb_ctx, bih_ctx, bhh_ctx,
                                       wihb_tgt, bih_tgt, bhh_tgt, b_gxw);
    k_word_g<<<66, 512, 0, stream>>>(lengths, order, h0w, c0w,
                                     whhb_ctx, whhb_tgt, b_gxw, emb);
  } else {
    k_word_s<<<66, 512, 0, stream>>>(words, lengths, order, h0w, c0w,
                                     wihb_ctx, whhb_ctx, bih_ctx, bhh_ctx,
                                     wihb_tgt, whhb_tgt, bih_tgt, bhh_tgt, emb);
  }
  k_gx<<<66, 512, 0, stream>>>(emb, wihb_prev, bih_prev, bhh_prev,
                               wihb_post, bih_post, bhh_post, gxp, gxq);
  k_sent<<<2, 512, 0, stream>>>(whhb_prev, whhb_post, h0p, c0p, h0q, c0q,
                                gxp, gxq, po, qo);
  k_fc<<<1, 256, 0, stream>>>(po, qo, fc_w, fc_b, (float*)d_out);
}

// Round 6
// 2414.985 us; speedup vs baseline: 1.7266x; 1.7266x over previous
//
#include <hip/hip_runtime.h>
#include <cmath>

typedef unsigned short u16;
typedef short bf16x8 __attribute__((ext_vector_type(8)));
typedef float f32x4 __attribute__((ext_vector_type(4)));

#define S_N 1025
#define W_N 128
#define H_N 200
#define FH_N 800
#define KP 232
#define SGP 911
#define SGW 900      // k_wrec sG row stride (floats); holds gates<896, %32=4 stagger
#define MID 512
#define NT 56
#define PKT (NT * 7 * 512)

__device__ __forceinline__ float bf2f(u16 u) {
  unsigned int x = ((unsigned int)u) << 16;
  return __builtin_bit_cast(float, x);
}
__device__ __forceinline__ u16 f2bf(float f) {
  unsigned int x = __builtin_bit_cast(unsigned int, f);
  x += 0x7fffu + ((x >> 16) & 1u);
  return (u16)(x >> 16);
}
#define LOG2E 1.44269504088896f
__device__ __forceinline__ float fsigm(float x) {
  float e = __builtin_amdgcn_exp2f(-fabsf(x) * LOG2E);
  float p = __builtin_amdgcn_rcpf(1.f + e);
  return x >= 0.f ? p : 1.f - p;
}
__device__ __forceinline__ float ftanh(float x) {
  float e = __builtin_amdgcn_exp2f(-2.f * fabsf(x) * LOG2E);
  float th = (1.f - e) * __builtin_amdgcn_rcpf(1.f + e);
  return x >= 0.f ? th : -th;
}

__device__ __forceinline__ const bf16x8* pkptr(const u16* pk, int tt, int kcc, int lane) {
  return (const bf16x8*)(pk + (size_t)((tt * 7 + kcc) * 512 + lane * 8));
}

// B-fragment scatter index for value at (row m 0..15, k 0..199):
// frag[kcc*512 + (quad_k*16 + m)*8 + jj] with k = kcc*32 + quad_k*8 + jj
__device__ __forceinline__ int bfidx(int m, int k) {
  return (k >> 5) * 512 + ((((k >> 3) & 3) * 16 + m) << 3) + (k & 7);
}

// ---------------------------------------------------------------------------
// Kernel 0: repack 8 fp32 weight matrices to bf16 MFMA fragment order.
// dst: [wih_ctx|whh_ctx|wih_tgt|whh_tgt|whh_prev|whh_post|wih_prev|wih_post]
// ---------------------------------------------------------------------------
__global__ __launch_bounds__(256) void k_w2b(
    const float* __restrict__ p0, const float* __restrict__ p1,
    const float* __restrict__ p2, const float* __restrict__ p3,
    const float* __restrict__ p4, const float* __restrict__ p5,
    const float* __restrict__ p6, const float* __restrict__ p7,
    u16* __restrict__ dst)
{
  int i = blockIdx.x * 256 + threadIdx.x;
  if (i >= 8 * PKT) return;
  int w = i / PKT, r = i - w * PKT;
  int tt = r / 3584;
  int q = r - tt * 3584;
  int kcc = q >> 9;
  int lane = (q >> 3) & 63;
  int j = q & 7;
  int col = lane & 15, quad = lane >> 4;
  int gate = tt * 16 + col;
  int k = kcc * 32 + quad * 8 + j;
  const float* ps[8] = {p0, p1, p2, p3, p4, p5, p6, p7};
  u16 v = 0;
  if (gate < FH_N && k < H_N) v = f2bf(ps[w][(size_t)gate * H_N + k]);
  dst[i] = v;
}

// ---------------------------------------------------------------------------
// Kernel 0b: bitonic sort of sentence ids by length (desc) -> order[]
// ---------------------------------------------------------------------------
__global__ __launch_bounds__(1024) void k_sort(
    const int* __restrict__ lengths, int* __restrict__ order)
{
  __shared__ int key[2048], val[2048];
  int tid = threadIdx.x;
  for (int v = 0; v < 2; ++v) {
    int i = tid + v * 1024;
    key[i] = (i < S_N) ? lengths[i] : -1;
    val[i] = (i < S_N) ? i : (S_N - 1);
  }
  __syncthreads();
  for (int k = 2; k <= 2048; k <<= 1)
    for (int j = k >> 1; j > 0; j >>= 1) {
      for (int v = 0; v < 2; ++v) {
        int i = tid + v * 1024;
        int ix = i ^ j;
        if (ix > i) {
          bool descRegion = ((i & k) == 0);
          int ki = key[i], kx = key[ix];
          if ((ki < kx) == descRegion) {
            key[i] = kx; key[ix] = ki;
            int tv = val[i]; val[i] = val[ix]; val[ix] = tv;
          }
        }
      }
      __syncthreads();
    }
  for (int v = 0; v < 2; ++v) {
    int i = tid + v * 1024;
    if (i < S_N) order[i] = val[i];
  }
}

// ---------------------------------------------------------------------------
// Kernel X: chunked input-projection GEMM.
// gxc[slot][tc][gate] = words[s][c*CH+tc] @ wih^T + (bih+bhh), tc in [0,CH).
// slot 0..1024 = ctx weights on sentence slot; slot 1025 = tgt weights on MID.
// grid = 1026 * TT blocks (TT 16-row t-tiles per chunk).
// ---------------------------------------------------------------------------
__global__ __launch_bounds__(512, 1) void k_xpack(
    int c, int CH,
    const float* __restrict__ words, const int* __restrict__ lengths,
    const u16* __restrict__ wihb_ctx, const float* __restrict__ bih_ctx, const float* __restrict__ bhh_ctx,
    const u16* __restrict__ wihb_tgt, const float* __restrict__ bih_tgt, const float* __restrict__ bhh_tgt,
    float* __restrict__ gxc)
{
  const int slot = blockIdx.x % 1026;
  const int tile = blockIdx.x / 1026;
  const int t0f = tile * 16;                 // t-offset within chunk
  const bool tg = (slot == 1025);
  const int s = tg ? MID : slot;
  const int len = lengths[s];
  const int tbase = c * CH + t0f;
  if (t0f >= CH || tbase >= len) return;
  const u16* wih = tg ? wihb_tgt : wihb_ctx;
  const float* bih = tg ? bih_tgt : bih_ctx;
  const float* bhh = tg ? bhh_tgt : bhh_ctx;

  __shared__ __align__(16) u16 sXh[7 * 512];
  __shared__ __align__(16) u16 sXl[7 * 512];
  __shared__ float sBias[FH_N];
  const int tid = threadIdx.x;
  for (int e = tid; e < 7 * 512; e += 512) { sXh[e] = 0; sXl[e] = 0; }
  for (int e = tid; e < FH_N; e += 512) sBias[e] = bih[e] + bhh[e];
  __syncthreads();
  const int nrow = min(16, min(CH - t0f, len - tbase));
  for (int e = tid; e < nrow * H_N; e += 512) {
    int tr = e / H_N, k = e - tr * H_N;
    float v = words[((size_t)s * W_N + tbase + tr) * H_N + k];
    u16 vh = f2bf(v);
    int idx = bfidx(tr, k);
    sXh[idx] = vh;
    sXl[idx] = f2bf(v - bf2f(vh));
  }
  __syncthreads();

  const int lane = tid & 63, wv = tid >> 6, quad = lane >> 4, col = lane & 15;
  f32x4 acc[7];
#pragma unroll
  for (int i = 0; i < 7; ++i) { f32x4 z = {0.f, 0.f, 0.f, 0.f}; acc[i] = z; }

#pragma unroll
  for (int kcc = 0; kcc < 7; ++kcc) {
    bf16x8 Aw[7];
#pragma unroll
    for (int i = 0; i < 7; ++i) Aw[i] = *pkptr(wih, wv + 8 * i, kcc, lane);
    bf16x8 bxh = *(const bf16x8*)(sXh + kcc * 512 + lane * 8);
    bf16x8 bxl = *(const bf16x8*)(sXl + kcc * 512 + lane * 8);
#pragma unroll
    for (int i = 0; i < 7; ++i) {
      acc[i] = __builtin_amdgcn_mfma_f32_16x16x32_bf16(Aw[i], bxh, acc[i], 0, 0, 0);
      acc[i] = __builtin_amdgcn_mfma_f32_16x16x32_bf16(Aw[i], bxl, acc[i], 0, 0, 0);
    }
  }

  // D[row=gate][col=t-row]; write 16B (4 consecutive gates) per tile
  const int tcg = t0f + col;                  // position within chunk
  const bool okcol = (tcg < CH) && (c * CH + tcg < len);
#pragma unroll
  for (int i = 0; i < 7; ++i) {
    int tt = wv + 8 * i;
    if (tt < 50 && okcol) {
      float bias0 = sBias[tt * 16 + quad * 4 + 0];
      float bias1 = sBias[tt * 16 + quad * 4 + 1];
      float bias2 = sBias[tt * 16 + quad * 4 + 2];
      float bias3 = sBias[tt * 16 + quad * 4 + 3];
      f32x4 o = {acc[i][0] + bias0, acc[i][1] + bias1, acc[i][2] + bias2, acc[i][3] + bias3};
      *(f32x4*)(gxc + ((size_t)slot * CH + tcg) * FH_N + tt * 16 + quad * 4) = o;
    }
  }
}

// ---------------------------------------------------------------------------
// Kernel R: chunked word-level recurrence. whh register-resident (afr[7][7],
// 196 VGPR @ (512,1) -> 256 budget). Per step: B = h hi/lo of 16 sentences
// (LDS frag layout), D[gate][sent] -> sG -> cell update; gx added from global
// in the epilogue. h/c state persists in ws across chunks.
// ---------------------------------------------------------------------------
__global__ __launch_bounds__(512, 1) void k_wrec(
    int c, int CH,
    const int* __restrict__ lengths, const int* __restrict__ order,
    const float* __restrict__ h0w, const float* __restrict__ c0w,
    const u16* __restrict__ whhb_ctx, const u16* __restrict__ whhb_tgt,
    const float* __restrict__ gxc,
    float* __restrict__ stateH, float* __restrict__ stateC,
    float* __restrict__ emb)
{
  const int tid = threadIdx.x;
  const int b = blockIdx.x;
  const bool is_tgt = (b == 65);
  const u16* whh = is_tgt ? whhb_tgt : whhb_ctx;

  __shared__ __align__(16) u16 sBh[7 * 512];
  __shared__ __align__(16) u16 sBl[7 * 512];
  __shared__ float sG[16 * SGW];
  __shared__ int sLen[16], sId[16];

  if (tid < 16) {
    int slot = b * 16 + tid;
    int s = is_tgt ? MID : order[min(slot, S_N - 1)];
    sId[tid] = s;
    sLen[tid] = lengths[s];
  }
  __syncthreads();
  int Lmax = 1;
  for (int m = 0; m < 16; ++m) Lmax = max(Lmax, sLen[m]);
  if (c * CH >= Lmax) return;   // block fully done in earlier chunks

  const int lane = tid & 63;
  const int wv = tid >> 6;
  const int quad = lane >> 4;
  const int col = lane & 15;

  bf16x8 afr[7][7];
#pragma unroll
  for (int i = 0; i < 7; ++i)
#pragma unroll
    for (int kcc = 0; kcc < 7; ++kcc)
      afr[i][kcc] = *pkptr(whh, wv + 8 * i, kcc, lane);

  for (int e = tid; e < 7 * 512; e += 512) { sBh[e] = 0; sBl[e] = 0; }
  __syncthreads();

  float creg[7];
#pragma unroll
  for (int rr = 0; rr < 7; ++rr) {
    int e = tid + 512 * rr;
    if (e < 16 * H_N) {
      int m = e / H_N, j = e - m * H_N;
      float h, cc;
      if (c == 0) {
        int s = sId[m];
        h = h0w[(size_t)s * H_N + j];
        cc = c0w[(size_t)s * H_N + j];
      } else {
        h = stateH[(size_t)(b * 16 + m) * H_N + j];
        cc = stateC[(size_t)(b * 16 + m) * H_N + j];
      }
      creg[rr] = cc;
      u16 hh = f2bf(h);
      int idx = bfidx(m, j);
      sBh[idx] = hh;
      sBl[idx] = f2bf(h - bf2f(hh));
    }
  }
  __syncthreads();

#pragma unroll 1
  for (int tc = 0; tc < CH; ++tc) {
    const int t = c * CH + tc;
    if (t >= Lmax) break;

    f32x4 acc[7];
#pragma unroll
    for (int i = 0; i < 7; ++i) { f32x4 z = {0.f, 0.f, 0.f, 0.f}; acc[i] = z; }
#pragma unroll
    for (int kcc = 0; kcc < 7; ++kcc) {
      bf16x8 bh = *(const bf16x8*)(sBh + kcc * 512 + lane * 8);
      bf16x8 bl = *(const bf16x8*)(sBl + kcc * 512 + lane * 8);
#pragma unroll
      for (int i = 0; i < 7; ++i) {
        acc[i] = __builtin_amdgcn_mfma_f32_16x16x32_bf16(afr[i][kcc], bh, acc[i], 0, 0, 0);
        acc[i] = __builtin_amdgcn_mfma_f32_16x16x32_bf16(afr[i][kcc], bl, acc[i], 0, 0, 0);
      }
    }
    // D[row=gate][col=sentence] -> sG[sent][gate]
#pragma unroll
    for (int i = 0; i < 7; ++i) {
      int tt = wv + 8 * i;
      *(f32x4*)(sG + col * SGW + tt * 16 + quad * 4) = acc[i];
    }
    __syncthreads();

    // cell update; gx read straight from global (coalesced per thread)
#pragma unroll
    for (int rr = 0; rr < 7; ++rr) {
      int e = tid + 512 * rr;
      if (e < 16 * H_N) {
        int m = e / H_N, j = e - m * H_N;
        int gslot = is_tgt ? 1025 : sId[m];
        const float* gp = gxc + ((size_t)gslot * CH + tc) * FH_N + j;
        const float* gRow = sG + m * SGW + j;
        float ig = gRow[0] + gp[0];
        float fg = gRow[H_N] + gp[H_N];
        float gg = gRow[2 * H_N] + gp[2 * H_N];
        float og = gRow[3 * H_N] + gp[3 * H_N];
        float nc = fsigm(fg) * creg[rr] + fsigm(ig) * ftanh(gg);
        float nh = fsigm(og) * ftanh(nc);
        creg[rr] = nc;
        u16 hh = f2bf(nh);
        int idx = bfidx(m, j);
        sBh[idx] = hh;
        sBl[idx] = f2bf(nh - bf2f(hh));
        if (t == sLen[m] - 1) {
          int s = sId[m];
          if (is_tgt) {
            if (m == 0) emb[(size_t)MID * H_N + j] = nh;
          } else if (s != MID) {
            emb[(size_t)s * H_N + j] = nh;
          }
        }
      }
    }
    __syncthreads();
  }

  // persist state (h reconstructed from hi+lo: identical to what MFMA sees)
#pragma unroll
  for (int rr = 0; rr < 7; ++rr) {
    int e = tid + 512 * rr;
    if (e < 16 * H_N) {
      int m = e / H_N, j = e - m * H_N;
      int idx = bfidx(m, j);
      stateH[(size_t)(b * 16 + m) * H_N + j] = bf2f(sBh[idx]) + bf2f(sBl[idx]);
      stateC[(size_t)(b * 16 + m) * H_N + j] = creg[rr];
    }
  }
}

// ---------------------------------------------------------------------------
// Fallback (tiny ws): round-5 streaming word kernel.
// ---------------------------------------------------------------------------
__global__ __launch_bounds__(512, 1) void k_word_s(
    const float* __restrict__ words, const int* __restrict__ lengths,
    const int* __restrict__ order,
    const float* __restrict__ h0w, const float* __restrict__ c0w,
    const u16* __restrict__ wihb_ctx, const u16* __restrict__ whhb_ctx,
    const float* __restrict__ bih_ctx, const float* __restrict__ bhh_ctx,
    const u16* __restrict__ wihb_tgt, const u16* __restrict__ whhb_tgt,
    const float* __restrict__ bih_tgt, const float* __restrict__ bhh_tgt,
    float* __restrict__ emb)
{
  const int tid = threadIdx.x;
  const int b = blockIdx.x;
  const bool is_tgt = (b == 65);
  const u16* wih = is_tgt ? wihb_tgt : wihb_ctx;
  const u16* whh = is_tgt ? whhb_tgt : whhb_ctx;
  const float* bih = is_tgt ? bih_tgt : bih_ctx;
  const float* bhh = is_tgt ? bhh_tgt : bhh_ctx;

  __shared__ __align__(16) u16 sXhi[16 * KP];
  __shared__ __align__(16) u16 sXlo[16 * KP];
  __shared__ __align__(16) u16 sHi[16 * KP];
  __shared__ __align__(16) u16 sLo[16 * KP];
  __shared__ float sG[8 * SGP];
  __shared__ float sB[4 * H_N];
  __shared__ int sLen[16], sId[16];

  for (int e = tid; e < 16 * KP; e += 512) {
    sXhi[e] = 0; sXlo[e] = 0; sHi[e] = 0; sLo[e] = 0;
  }
  if (tid < 16) {
    int slot = b * 16 + tid;
    int s = is_tgt ? MID : order[min(slot, S_N - 1)];
    sId[tid] = s;
    sLen[tid] = lengths[s];
  }
  for (int e = tid; e < 4 * H_N; e += 512) sB[e] = bih[e] + bhh[e];
  __syncthreads();

  float creg[7];
#pragma unroll
  for (int r = 0; r < 7; ++r) {
    int e = tid + 512 * r;
    if (e < 16 * H_N) {
      int m = e / H_N, j = e - m * H_N;
      int s = sId[m];
      float h = h0w[(size_t)s * H_N + j];
      u16 hh = f2bf(h);
      sHi[m * KP + j] = hh;
      sLo[m * KP + j] = f2bf(h - bf2f(hh));
      creg[r] = c0w[(size_t)s * H_N + j];
    }
  }
  __syncthreads();
  int Lmax = 1;
  for (int m = 0; m < 16; ++m) Lmax = max(Lmax, sLen[m]);

  const int lane = tid & 63;
  const int wv = tid >> 6;
  const int quad = lane >> 4;
  const int col = lane & 15;
  const int hpass = quad >> 1;

  const u16* aXh = sXhi + col * KP + quad * 8;
  const u16* aXl = sXlo + col * KP + quad * 8;
  const u16* aHh = sHi  + col * KP + quad * 8;
  const u16* aHl = sLo  + col * KP + quad * 8;

#pragma unroll 1
  for (int t = 0; t < Lmax; ++t) {
    for (int e = tid; e < 16 * H_N; e += 512) {
      int m = e / H_N, k = e - m * H_N;
      float v = words[((size_t)sId[m] * W_N + t) * H_N + k];
      u16 vh = f2bf(v);
      sXhi[m * KP + k] = vh;
      sXlo[m * KP + k] = f2bf(v - bf2f(vh));
    }
    __syncthreads();

    f32x4 acc[7];
#pragma unroll
    for (int i = 0; i < 7; ++i) { f32x4 z4 = {0.f, 0.f, 0.f, 0.f}; acc[i] = z4; }

#pragma unroll
    for (int kcc = 0; kcc < 7; ++kcc) {
      bf16x8 axh = *(const bf16x8*)(aXh + kcc * 32);
      bf16x8 axl = *(const bf16x8*)(aXl + kcc * 32);
      bf16x8 ahh = *(const bf16x8*)(aHh + kcc * 32);
      bf16x8 ahl = *(const bf16x8*)(aHl + kcc * 32);
#pragma unroll
      for (int i = 0; i < 7; ++i) {
        bf16x8 bw = *pkptr(wih, wv + 8 * i, kcc, lane);
        bf16x8 bh = *pkptr(whh, wv + 8 * i, kcc, lane);
        acc[i] = __builtin_amdgcn_mfma_f32_16x16x32_bf16(axh, bw, acc[i], 0, 0, 0);
        acc[i] = __builtin_amdgcn_mfma_f32_16x16x32_bf16(axl, bw, acc[i], 0, 0, 0);
        acc[i] = __builtin_amdgcn_mfma_f32_16x16x32_bf16(ahh, bh, acc[i], 0, 0, 0);
        acc[i] = __builtin_amdgcn_mfma_f32_16x16x32_bf16(ahl, bh, acc[i], 0, 0, 0);
      }
    }

#pragma unroll 1
    for (int h = 0; h < 2; ++h) {
      if (hpass == h) {
#pragma unroll
        for (int i = 0; i < 7; ++i) {
          int tt = wv + 8 * i;
#pragma unroll
          for (int r = 0; r < 4; ++r)
            sG[((quad & 1) * 4 + r) * SGP + tt * 16 + col] = acc[i][r];
        }
      }
      __syncthreads();
#pragma unroll
      for (int rr = 0; rr < 7; ++rr) {
        int e = tid + 512 * rr;
        if (e < 16 * H_N) {
          int m = e / H_N, j = e - m * H_N;
          if ((m >> 3) == h) {
            const float* gRow = sG + (m - 8 * h) * SGP;
            float ig = gRow[j] + sB[j];
            float fg = gRow[H_N + j] + sB[H_N + j];
            float gg = gRow[2 * H_N + j] + sB[2 * H_N + j];
            float og = gRow[3 * H_N + j] + sB[3 * H_N + j];
            float nc = fsigm(fg) * creg[rr] + fsigm(ig) * ftanh(gg);
            float nh = fsigm(og) * ftanh(nc);
            creg[rr] = nc;
            u16 hh = f2bf(nh);
            sHi[m * KP + j] = hh;
            sLo[m * KP + j] = f2bf(nh - bf2f(hh));
            if (t == sLen[m] - 1) {
              int s = sId[m];
              if (is_tgt) {
                if (m == 0) emb[(size_t)MID * H_N + j] = nh;
              } else if (s != MID) {
                emb[(size_t)s * H_N + j] = nh;
              }
            }
          }
        }
      }
      __syncthreads();
    }
  }
}

// ---------------------------------------------------------------------------
// Kernel 2: gx projections for prev/post via MFMA (packed wih).
// ---------------------------------------------------------------------------
__global__ __launch_bounds__(512) void k_gx(
    const float* __restrict__ emb,
    const u16* __restrict__ wihb_prev, const float* __restrict__ bih_prev, const float* __restrict__ bhh_prev,
    const u16* __restrict__ wihb_post, const float* __restrict__ bih_post, const float* __restrict__ bhh_post,
    float* __restrict__ gxp, float* __restrict__ gxq)
{
  const int tid = threadIdx.x;
  const int b = blockIdx.x;
  const bool post = (b >= 33);
  const int t0 = (post ? b - 33 : b) * 16;
  const u16* wih = post ? wihb_post : wihb_prev;
  const float* bih = post ? bih_post : bih_prev;
  const float* bhh = post ? bhh_post : bhh_prev;
  float* out = post ? gxq : gxp;

  __shared__ __align__(16) u16 sEhi[16 * KP];
  __shared__ __align__(16) u16 sElo[16 * KP];
  for (int e = tid; e < 16 * KP; e += 512) { sEhi[e] = 0; sElo[e] = 0; }
  __syncthreads();
  for (int e = tid; e < 16 * H_N; e += 512) {
    int m = e / H_N, k = e - m * H_N;
    int t = t0 + m;
    if (t <= 512) {
      int src = post ? (1024 - t) : t;
      float v = emb[(size_t)src * H_N + k];
      u16 vh = f2bf(v);
      sEhi[m * KP + k] = vh;
      sElo[m * KP + k] = f2bf(v - bf2f(vh));
    }
  }
  __syncthreads();

  const int lane = tid & 63;
  const int wv = tid >> 6;
  const int quad = lane >> 4;
  const int col = lane & 15;
  const u16* aH = sEhi + col * KP + quad * 8;
  const u16* aL = sElo + col * KP + quad * 8;

#pragma unroll 1
  for (int i = 0; i < 7; ++i) {
    int tt = wv + 8 * i;
    if (tt >= 50) break;
    int gate = tt * 16 + col;
    f32x4 acc = {0.f, 0.f, 0.f, 0.f};
#pragma unroll
    for (int kcc = 0; kcc < 7; ++kcc) {
      bf16x8 Ah = *(const bf16x8*)(aH + kcc * 32);
      bf16x8 Al = *(const bf16x8*)(aL + kcc * 32);
      bf16x8 bw = *pkptr(wih, tt, kcc, lane);
      acc = __builtin_amdgcn_mfma_f32_16x16x32_bf16(Ah, bw, acc, 0, 0, 0);
      acc = __builtin_amdgcn_mfma_f32_16x16x32_bf16(Al, bw, acc, 0, 0, 0);
    }
    float bias = bih[gate] + bhh[gate];
#pragma unroll
    for (int r = 0; r < 4; ++r) {
      int t = t0 + quad * 4 + r;
      if (t <= 512) out[(size_t)t * FH_N + gate] = acc[r] + bias;
    }
  }
}

// ---------------------------------------------------------------------------
// Kernel 3: prev/post sentence LSTMs, 513 serial steps. (512,1) -> 256 VGPR
// budget so afr[7][7] (196) is truly register-resident.
// ---------------------------------------------------------------------------
__global__ __launch_bounds__(512, 1) void k_sent(
    const u16* __restrict__ whhb_prev, const u16* __restrict__ whhb_post,
    const float* __restrict__ h0p, const float* __restrict__ c0p,
    const float* __restrict__ h0q, const float* __restrict__ c0q,
    const float* __restrict__ gxp, const float* __restrict__ gxq,
    float* __restrict__ outp, float* __restrict__ outq)
{
  const int tid = threadIdx.x;
  const bool post = (blockIdx.x != 0);
  const u16* whh = post ? whhb_post : whhb_prev;
  const float* h0 = post ? h0q : h0p;
  const float* c0 = post ? c0q : c0p;
  const float* gx = post ? gxq : gxp;
  float* outv = post ? outq : outp;

  __shared__ __align__(16) u16 sHi[224];
  __shared__ __align__(16) u16 sLo[224];
  __shared__ float sGa[FH_N];
  __shared__ float sGb[FH_N];

  const int lane = tid & 63;
  const int wv = tid >> 6;
  const int quad = lane >> 4;
  const int col = lane & 15;

  bf16x8 afr[7][7];
#pragma unroll
  for (int i = 0; i < 7; ++i)
#pragma unroll
    for (int kcc = 0; kcc < 7; ++kcc)
      afr[i][kcc] = *pkptr(whh, wv + 8 * i, kcc, lane);

  if (tid < 224) { sHi[tid] = 0; sLo[tid] = 0; }
  float c = 0.f, last_h = 0.f;
  if (tid < H_N) {
    float h = h0[tid];
    u16 hh = f2bf(h);
    sHi[tid] = hh;
    sLo[tid] = f2bf(h - bf2f(hh));
    c = c0[tid];
  }
  __syncthreads();

  const u16* hb = ((lane & 8) ? sLo : sHi) + quad * 8;
  const bool wrA = (col == 0), wrB = (col == 8);

#pragma unroll 1
  for (int t = 0; t < 513; ++t) {
    bf16x8 bfr[7];
#pragma unroll
    for (int kcc = 0; kcc < 7; ++kcc) bfr[kcc] = *(const bf16x8*)(hb + kcc * 32);

#pragma unroll
    for (int i = 0; i < 7; ++i) {
      int tt = wv + 8 * i;
      f32x4 acc = {0.f, 0.f, 0.f, 0.f};
#pragma unroll
      for (int kcc = 0; kcc < 7; ++kcc)
        acc = __builtin_amdgcn_mfma_f32_16x16x32_bf16(afr[i][kcc], bfr[kcc], acc, 0, 0, 0);
      if (tt < 50) {
        if (wrA) {
#pragma unroll
          for (int r = 0; r < 4; ++r) sGa[tt * 16 + quad * 4 + r] = acc[r];
        } else if (wrB) {
#pragma unroll
          for (int r = 0; r < 4; ++r) sGb[tt * 16 + quad * 4 + r] = acc[r];
        }
      }
    }
    __syncthreads();

    if (tid < H_N) {
      const float* g = gx + (size_t)t * FH_N;
      float ig = sGa[tid] + sGb[tid] + g[tid];
      float fg = sGa[H_N + tid] + sGb[H_N + tid] + g[H_N + tid];
      float gg = sGa[2 * H_N + tid] + sGb[2 * H_N + tid] + g[2 * H_N + tid];
      float og = sGa[3 * H_N + tid] + sGb[3 * H_N + tid] + g[3 * H_N + tid];
      float nc = fsigm(fg) * c + fsigm(ig) * ftanh(gg);
      float nh = fsigm(og) * ftanh(nc);
      c = nc;
      last_h = nh;
      u16 hh = f2bf(nh);
      sHi[tid] = hh;
      sLo[tid] = f2bf(nh - bf2f(hh));
    }
    __syncthreads();
  }
  if (tid < H_N) outv[tid] = last_h;
}

// ---------------------------------------------------------------------------
// Kernel 4: out = [prev_out ; post_out] @ fc_w^T + fc_b
// ---------------------------------------------------------------------------
__global__ __launch_bounds__(256) void k_fc(
    const float* __restrict__ pout, const float* __restrict__ qout,
    const float* __restrict__ fc_w, const float* __restrict__ fc_b,
    float* __restrict__ out)
{
  const int tid = threadIdx.x;
  if (tid < H_N) {
    float d = fc_b[tid];
    const float* wr = fc_w + (size_t)tid * 2 * H_N;
    for (int k = 0; k < H_N; ++k) d += pout[k] * wr[k];
    for (int k = 0; k < H_N; ++k) d += qout[k] * wr[H_N + k];
    out[tid] = d;
  }
}

extern "C" void kernel_launch(void* const* d_in, const int* in_sizes, int n_in,
                              void* d_out, int out_size, void* d_ws, size_t ws_size,
                              hipStream_t stream) {
  const float* words   = (const float*)d_in[0];
  const int*   lengths = (const int*)d_in[1];
  const float* h0w = (const float*)d_in[2];
  const float* c0w = (const float*)d_in[3];
  const float* h0p = (const float*)d_in[4];
  const float* c0p = (const float*)d_in[5];
  const float* h0q = (const float*)d_in[6];
  const float* c0q = (const float*)d_in[7];
  const float* wih_ctx = (const float*)d_in[8];
  const float* whh_ctx = (const float*)d_in[9];
  const float* bih_ctx = (const float*)d_in[10];
  const float* bhh_ctx = (const float*)d_in[11];
  const float* wih_tgt = (const float*)d_in[12];
  const float* whh_tgt = (const float*)d_in[13];
  const float* bih_tgt = (const float*)d_in[14];
  const float* bhh_tgt = (const float*)d_in[15];
  const float* wih_prev = (const float*)d_in[16];
  const float* whh_prev = (const float*)d_in[17];
  const float* bih_prev = (const float*)d_in[18];
  const float* bhh_prev = (const float*)d_in[19];
  const float* wih_post = (const float*)d_in[20];
  const float* whh_post = (const float*)d_in[21];
  const float* bih_post = (const float*)d_in[22];
  const float* bhh_post = (const float*)d_in[23];
  const float* fc_w = (const float*)d_in[24];
  const float* fc_b = (const float*)d_in[25];
  (void)in_sizes; (void)n_in; (void)out_size;

  // fixed tail (floats): stateH 211200 | stateC 211200 | emb 205000 |
  // gxp 410400 | gxq 410400 | po 200 | qo 200  = 1,448,600 floats
  const size_t FIXF = 1448600;
  // pick largest chunk CH whose gxc fits: gxc = 1026*CH*800 floats
  int CH = 0;
  for (int cand = 32; cand >= 1; cand >>= 1) {
    size_t needB = ((size_t)1026 * cand * 800 + FIXF) * 4 + 1056 * 4 + (size_t)8 * PKT * 2 + 256;
    if (ws_size >= needB) { CH = cand; break; }
  }

  float* ws = (float*)d_ws;
  float *gxc, *stateH, *stateC, *emb, *gxp, *gxq, *po, *qo;
  int* order;
  u16* wb;
  if (CH > 0) {
    gxc = ws;
    stateH = gxc + (size_t)1026 * CH * 800;
    stateC = stateH + 211200;
    emb = stateC + 211200;
    gxp = emb + 205000;
    gxq = gxp + 410400;
    po = gxq + 410400;
    qo = po + 200;
    order = (int*)(qo + 200);
    wb = (u16*)(order + 1056);
  } else {
    gxc = nullptr; stateH = nullptr; stateC = nullptr;
    emb = ws;
    gxp = ws + 205000;
    gxq = ws + 615400;
    po = ws + 1025800;
    qo = ws + 1026000;
    order = (int*)(ws + 1026200);
    wb = (u16*)(ws + 1027232);
  }
  u16* wihb_ctx  = wb;
  u16* whhb_ctx  = wb + PKT;
  u16* wihb_tgt  = wb + 2 * PKT;
  u16* whhb_tgt  = wb + 3 * PKT;
  u16* whhb_prev = wb + 4 * PKT;
  u16* whhb_post = wb + 5 * PKT;
  u16* wihb_prev = wb + 6 * PKT;
  u16* wihb_post = wb + 7 * PKT;

  k_w2b<<<(8 * PKT + 255) / 256, 256, 0, stream>>>(
      wih_ctx, whh_ctx, wih_tgt, whh_tgt, whh_prev, whh_post,
      wih_prev, wih_post, wb);
  k_sort<<<1, 1024, 0, stream>>>(lengths, order);

  if (CH > 0) {
    const int TT = (CH + 15) / 16;
    const int NC = (W_N + CH - 1) / CH;
    for (int c = 0; c < NC; ++c) {
      k_xpack<<<1026 * TT, 512, 0, stream>>>(c, CH, words, lengths,
                                             wihb_ctx, bih_ctx, bhh_ctx,
                                             wihb_tgt, bih_tgt, bhh_tgt, gxc);
      k_wrec<<<66, 512, 0, stream>>>(c, CH, lengths, order, h0w, c0w,
                                     whhb_ctx, whhb_tgt, gxc, stateH, stateC, emb);
    }
  } else {
    k_word_s<<<66, 512, 0, stream>>>(words, lengths, order, h0w, c0w,
                                     wihb_ctx, whhb_ctx, bih_ctx, bhh_ctx,
                                     wihb_tgt, whhb_tgt, bih_tgt, bhh_tgt, emb);
  }
  k_gx<<<66, 512, 0, stream>>>(emb, wihb_prev, bih_prev, bhh_prev,
                               wihb_post, bih_post, bhh_post, gxp, gxq);
  k_sent<<<2, 512, 0, stream>>>(whhb_prev, whhb_post, h0p, c0p, h0q, c0q,
                                gxp, gxq, po, qo);
  k_fc<<<1, 256, 0, stream>>>(po, qo, fc_w, fc_b, (float*)d_out);
}

// Round 7
// 2143.441 us; speedup vs baseline: 1.9454x; 1.1267x over previous
//
#include <hip/hip_runtime.h>
#include <cmath>

typedef unsigned short u16;
typedef short bf16x8 __attribute__((ext_vector_type(8)));
typedef float f32x4 __attribute__((ext_vector_type(4)));

#define S_N 1025
#define W_N 128
#define H_N 200
#define FH_N 800
#define KP 232
#define SGP 911
#define SGW 804      // wrec sG row stride (floats); 804%32=4 stagger, gates<800
#define MID 512
#define NT 56
#define PKT (NT * 7 * 512)
// conflict-free LDS B-fragment layout: per-kcc stride 544 u16, per-quadk 136
#define PKC 544
#define QKS 136
#define FRAGSZ (7 * PKC)   // 3808 u16 per array

__device__ __forceinline__ float bf2f(u16 u) {
  unsigned int x = ((unsigned int)u) << 16;
  return __builtin_bit_cast(float, x);
}
__device__ __forceinline__ u16 f2bf(float f) {
  unsigned int x = __builtin_bit_cast(unsigned int, f);
  x += 0x7fffu + ((x >> 16) & 1u);
  return (u16)(x >> 16);
}
#define LOG2E 1.44269504088896f
__device__ __forceinline__ float fsigm(float x) {
  float e = __builtin_amdgcn_exp2f(-fabsf(x) * LOG2E);
  float p = __builtin_amdgcn_rcpf(1.f + e);
  return x >= 0.f ? p : 1.f - p;
}
__device__ __forceinline__ float ftanh(float x) {
  float e = __builtin_amdgcn_exp2f(-2.f * fabsf(x) * LOG2E);
  float th = (1.f - e) * __builtin_amdgcn_rcpf(1.f + e);
  return x >= 0.f ? th : -th;
}

__device__ __forceinline__ const bf16x8* pkptr(const u16* pk, int tt, int kcc, int lane) {
  return (const bf16x8*)(pk + (size_t)((tt * 7 + kcc) * 512 + lane * 8));
}
// writer: element (row m 0..15, k 0..199) -> padded LDS fragment index
__device__ __forceinline__ int fidx(int m, int k) {
  return (k >> 5) * PKC + ((k >> 3) & 3) * QKS + m * 8 + (k & 7);
}
// reader: lane's 16B fragment for k-chunk kcc (16B-aligned: QKS*2=272=17*16)
__device__ __forceinline__ const bf16x8* frg(const u16* base, int kcc, int lane) {
  return (const bf16x8*)(base + kcc * PKC + (lane >> 4) * QKS + (lane & 15) * 8);
}

// ---------------------------------------------------------------------------
// Kernel 0: repack 8 fp32 weight matrices to bf16 MFMA fragment order.
// dst: [wih_ctx|whh_ctx|wih_tgt|whh_tgt|whh_prev|whh_post|wih_prev|wih_post]
// ---------------------------------------------------------------------------
__global__ __launch_bounds__(256) void k_w2b(
    const float* __restrict__ p0, const float* __restrict__ p1,
    const float* __restrict__ p2, const float* __restrict__ p3,
    const float* __restrict__ p4, const float* __restrict__ p5,
    const float* __restrict__ p6, const float* __restrict__ p7,
    u16* __restrict__ dst)
{
  int i = blockIdx.x * 256 + threadIdx.x;
  if (i >= 8 * PKT) return;
  int w = i / PKT, r = i - w * PKT;
  int tt = r / 3584;
  int q = r - tt * 3584;
  int kcc = q >> 9;
  int lane = (q >> 3) & 63;
  int j = q & 7;
  int col = lane & 15, quad = lane >> 4;
  int gate = tt * 16 + col;
  int k = kcc * 32 + quad * 8 + j;
  const float* ps[8] = {p0, p1, p2, p3, p4, p5, p6, p7};
  u16 v = 0;
  if (gate < FH_N && k < H_N) v = f2bf(ps[w][(size_t)gate * H_N + k]);
  dst[i] = v;
}

// ---------------------------------------------------------------------------
// Kernel 0b: bitonic sort of sentence ids by length (desc) -> order[]
// ---------------------------------------------------------------------------
__global__ __launch_bounds__(1024) void k_sort(
    const int* __restrict__ lengths, int* __restrict__ order)
{
  __shared__ int key[2048], val[2048];
  int tid = threadIdx.x;
  for (int v = 0; v < 2; ++v) {
    int i = tid + v * 1024;
    key[i] = (i < S_N) ? lengths[i] : -1;
    val[i] = (i < S_N) ? i : (S_N - 1);
  }
  __syncthreads();
  for (int k = 2; k <= 2048; k <<= 1)
    for (int j = k >> 1; j > 0; j >>= 1) {
      for (int v = 0; v < 2; ++v) {
        int i = tid + v * 1024;
        int ix = i ^ j;
        if (ix > i) {
          bool descRegion = ((i & k) == 0);
          int ki = key[i], kx = key[ix];
          if ((ki < kx) == descRegion) {
            key[i] = kx; key[ix] = ki;
            int tv = val[i]; val[i] = val[ix]; val[ix] = tv;
          }
        }
      }
      __syncthreads();
    }
  for (int v = 0; v < 2; ++v) {
    int i = tid + v * 1024;
    if (i < S_N) order[i] = val[i];
  }
}

// ---------------------------------------------------------------------------
// Kernel X: chunked input-projection GEMM (conflict-free staging layout).
// gxc[slot][tc][gate] = words[s][c*CH+tc] @ wih^T + (bih+bhh).
// slot 0..1024 = ctx on sentence slot; slot 1025 = tgt on MID.
// ---------------------------------------------------------------------------
__global__ __launch_bounds__(512, 1) void k_xpack(
    int c, int CH,
    const float* __restrict__ words, const int* __restrict__ lengths,
    const u16* __restrict__ wihb_ctx, const float* __restrict__ bih_ctx, const float* __restrict__ bhh_ctx,
    const u16* __restrict__ wihb_tgt, const float* __restrict__ bih_tgt, const float* __restrict__ bhh_tgt,
    float* __restrict__ gxc)
{
  const int slot = blockIdx.x % 1026;
  const int tile = blockIdx.x / 1026;
  const int t0f = tile * 16;
  const bool tg = (slot == 1025);
  const int s = tg ? MID : slot;
  const int len = lengths[s];
  const int tbase = c * CH + t0f;
  if (t0f >= CH || tbase >= len) return;
  const u16* wih = tg ? wihb_tgt : wihb_ctx;
  const float* bih = tg ? bih_tgt : bih_ctx;
  const float* bhh = tg ? bhh_tgt : bhh_ctx;

  __shared__ __align__(16) u16 sXh[FRAGSZ];
  __shared__ __align__(16) u16 sXl[FRAGSZ];
  __shared__ float sBias[FH_N];
  const int tid = threadIdx.x;
  for (int e = tid; e < FRAGSZ; e += 512) { sXh[e] = 0; sXl[e] = 0; }
  for (int e = tid; e < FH_N; e += 512) sBias[e] = bih[e] + bhh[e];
  __syncthreads();
  const int nrow = min(16, min(CH - t0f, len - tbase));
  for (int e = tid; e < nrow * H_N; e += 512) {
    int tr = e / H_N, k = e - tr * H_N;
    float v = words[((size_t)s * W_N + tbase + tr) * H_N + k];
    u16 vh = f2bf(v);
    int idx = fidx(tr, k);
    sXh[idx] = vh;
    sXl[idx] = f2bf(v - bf2f(vh));
  }
  __syncthreads();

  const int lane = tid & 63, wv = tid >> 6, quad = lane >> 4, col = lane & 15;
  const int tcg = t0f + col;
  const bool okcol = (tcg < CH) && (c * CH + tcg < len);

#pragma unroll
  for (int i = 0; i < 7; ++i) {
    int tt = wv + 8 * i;
    if (tt < 50) {                      // wave-uniform: skip pad tiles
      f32x4 acc = {0.f, 0.f, 0.f, 0.f};
#pragma unroll
      for (int kcc = 0; kcc < 7; ++kcc) {
        bf16x8 Aw = *pkptr(wih, tt, kcc, lane);
        bf16x8 bxh = *frg(sXh, kcc, lane);
        bf16x8 bxl = *frg(sXl, kcc, lane);
        acc = __builtin_amdgcn_mfma_f32_16x16x32_bf16(Aw, bxh, acc, 0, 0, 0);
        acc = __builtin_amdgcn_mfma_f32_16x16x32_bf16(Aw, bxl, acc, 0, 0, 0);
      }
      if (okcol) {
        float b0 = sBias[tt * 16 + quad * 4 + 0];
        float b1 = sBias[tt * 16 + quad * 4 + 1];
        float b2 = sBias[tt * 16 + quad * 4 + 2];
        float b3 = sBias[tt * 16 + quad * 4 + 3];
        f32x4 o = {acc[0] + b0, acc[1] + b1, acc[2] + b2, acc[3] + b3};
        *(f32x4*)(gxc + ((size_t)slot * CH + tcg) * FH_N + tt * 16 + quad * 4) = o;
      }
    }
  }
}

// ---------------------------------------------------------------------------
// Kernel R: chunked word-level recurrence. whh register/AGPR-resident
// afr[7][7]; B = 16 sentences' h (hi/lo) in the conflict-free frag layout.
// gx loads issued after acc->sG (acc regs freed), consumed post-barrier.
// ---------------------------------------------------------------------------
__global__ __launch_bounds__(512, 1) void k_wrec(
    int c, int CH,
    const int* __restrict__ lengths, const int* __restrict__ order,
    const float* __restrict__ h0w, const float* __restrict__ c0w,
    const u16* __restrict__ whhb_ctx, const u16* __restrict__ whhb_tgt,
    const float* __restrict__ gxc,
    float* __restrict__ stateH, float* __restrict__ stateC,
    float* __restrict__ emb)
{
  const int tid = threadIdx.x;
  const int b = blockIdx.x;
  const bool is_tgt = (b == 65);
  const u16* whh = is_tgt ? whhb_tgt : whhb_ctx;

  __shared__ __align__(16) u16 sBh[FRAGSZ];
  __shared__ __align__(16) u16 sBl[FRAGSZ];
  __shared__ float sG[16 * SGW];
  __shared__ int sLen[16], sId[16];

  if (tid < 16) {
    int slot = b * 16 + tid;
    int s = is_tgt ? MID : order[min(slot, S_N - 1)];
    sId[tid] = s;
    sLen[tid] = lengths[s];
  }
  __syncthreads();
  int Lmax = 1;
  for (int m = 0; m < 16; ++m) Lmax = max(Lmax, sLen[m]);
  if (c * CH >= Lmax) return;

  const int lane = tid & 63;
  const int wv = tid >> 6;
  const int quad = lane >> 4;
  const int col = lane & 15;

  bf16x8 afr[7][7];
#pragma unroll
  for (int i = 0; i < 7; ++i)
#pragma unroll
    for (int kcc = 0; kcc < 7; ++kcc)
      afr[i][kcc] = *pkptr(whh, wv + 8 * i, kcc, lane);

  for (int e = tid; e < FRAGSZ; e += 512) { sBh[e] = 0; sBl[e] = 0; }
  __syncthreads();

  float creg[7];
#pragma unroll
  for (int rr = 0; rr < 7; ++rr) {
    int e = tid + 512 * rr;
    if (e < 16 * H_N) {
      int m = e / H_N, j = e - m * H_N;
      float h, cc;
      if (c == 0) {
        int s = sId[m];
        h = h0w[(size_t)s * H_N + j];
        cc = c0w[(size_t)s * H_N + j];
      } else {
        h = stateH[(size_t)(b * 16 + m) * H_N + j];
        cc = stateC[(size_t)(b * 16 + m) * H_N + j];
      }
      creg[rr] = cc;
      u16 hh = f2bf(h);
      int idx = fidx(m, j);
      sBh[idx] = hh;
      sBl[idx] = f2bf(h - bf2f(hh));
    }
  }
  __syncthreads();

#pragma unroll 1
  for (int tc = 0; tc < CH; ++tc) {
    const int t = c * CH + tc;
    if (t >= Lmax) break;

    f32x4 acc[7];
#pragma unroll
    for (int i = 0; i < 7; ++i) { f32x4 z = {0.f, 0.f, 0.f, 0.f}; acc[i] = z; }
#pragma unroll
    for (int kcc = 0; kcc < 7; ++kcc) {
      bf16x8 bh = *frg(sBh, kcc, lane);
      bf16x8 bl = *frg(sBl, kcc, lane);
#pragma unroll
      for (int i = 0; i < 7; ++i) {
        if (wv + 8 * i < 50) {          // wave-uniform: skip pad tiles
          acc[i] = __builtin_amdgcn_mfma_f32_16x16x32_bf16(afr[i][kcc], bh, acc[i], 0, 0, 0);
          acc[i] = __builtin_amdgcn_mfma_f32_16x16x32_bf16(afr[i][kcc], bl, acc[i], 0, 0, 0);
        }
      }
    }
#pragma unroll
    for (int i = 0; i < 7; ++i) {
      int tt = wv + 8 * i;
      if (tt < 50)
        *(f32x4*)(sG + col * SGW + tt * 16 + quad * 4) = acc[i];
    }

    // issue gx loads now (acc freed); latency overlaps the barrier drain
    float gv[7][4];
#pragma unroll
    for (int rr = 0; rr < 7; ++rr) {
      int e = tid + 512 * rr;
      if (e < 16 * H_N) {
        int m = e / H_N, j = e - m * H_N;
        int gslot = is_tgt ? 1025 : sId[m];
        const float* gp = gxc + ((size_t)gslot * CH + tc) * FH_N + j;
        gv[rr][0] = gp[0];
        gv[rr][1] = gp[H_N];
        gv[rr][2] = gp[2 * H_N];
        gv[rr][3] = gp[3 * H_N];
      }
    }
    __syncthreads();

#pragma unroll
    for (int rr = 0; rr < 7; ++rr) {
      int e = tid + 512 * rr;
      if (e < 16 * H_N) {
        int m = e / H_N, j = e - m * H_N;
        const float* gRow = sG + m * SGW + j;
        float ig = gRow[0] + gv[rr][0];
        float fg = gRow[H_N] + gv[rr][1];
        float gg = gRow[2 * H_N] + gv[rr][2];
        float og = gRow[3 * H_N] + gv[rr][3];
        float nc = fsigm(fg) * creg[rr] + fsigm(ig) * ftanh(gg);
        float nh = fsigm(og) * ftanh(nc);
        creg[rr] = nc;
        u16 hh = f2bf(nh);
        int idx = fidx(m, j);
        sBh[idx] = hh;
        sBl[idx] = f2bf(nh - bf2f(hh));
        if (t == sLen[m] - 1) {
          int s = sId[m];
          if (is_tgt) {
            if (m == 0) emb[(size_t)MID * H_N + j] = nh;
          } else if (s != MID) {
            emb[(size_t)s * H_N + j] = nh;
          }
        }
      }
    }
    __syncthreads();
  }

#pragma unroll
  for (int rr = 0; rr < 7; ++rr) {
    int e = tid + 512 * rr;
    if (e < 16 * H_N) {
      int m = e / H_N, j = e - m * H_N;
      int idx = fidx(m, j);
      stateH[(size_t)(b * 16 + m) * H_N + j] = bf2f(sBh[idx]) + bf2f(sBl[idx]);
      stateC[(size_t)(b * 16 + m) * H_N + j] = creg[rr];
    }
  }
}

// ---------------------------------------------------------------------------
// Fallback (tiny ws): streaming word kernel (round-5 style, unchanged).
// ---------------------------------------------------------------------------
__global__ __launch_bounds__(512, 1) void k_word_s(
    const float* __restrict__ words, const int* __restrict__ lengths,
    const int* __restrict__ order,
    const float* __restrict__ h0w, const float* __restrict__ c0w,
    const u16* __restrict__ wihb_ctx, const u16* __restrict__ whhb_ctx,
    const float* __restrict__ bih_ctx, const float* __restrict__ bhh_ctx,
    const u16* __restrict__ wihb_tgt, const u16* __restrict__ whhb_tgt,
    const float* __restrict__ bih_tgt, const float* __restrict__ bhh_tgt,
    float* __restrict__ emb)
{
  const int tid = threadIdx.x;
  const int b = blockIdx.x;
  const bool is_tgt = (b == 65);
  const u16* wih = is_tgt ? wihb_tgt : wihb_ctx;
  const u16* whh = is_tgt ? whhb_tgt : whhb_ctx;
  const float* bih = is_tgt ? bih_tgt : bih_ctx;
  const float* bhh = is_tgt ? bhh_tgt : bhh_ctx;

  __shared__ __align__(16) u16 sXhi[16 * KP];
  __shared__ __align__(16) u16 sXlo[16 * KP];
  __shared__ __align__(16) u16 sHi[16 * KP];
  __shared__ __align__(16) u16 sLo[16 * KP];
  __shared__ float sG[8 * SGP];
  __shared__ float sB[4 * H_N];
  __shared__ int sLen[16], sId[16];

  for (int e = tid; e < 16 * KP; e += 512) {
    sXhi[e] = 0; sXlo[e] = 0; sHi[e] = 0; sLo[e] = 0;
  }
  if (tid < 16) {
    int slot = b * 16 + tid;
    int s = is_tgt ? MID : order[min(slot, S_N - 1)];
    sId[tid] = s;
    sLen[tid] = lengths[s];
  }
  for (int e = tid; e < 4 * H_N; e += 512) sB[e] = bih[e] + bhh[e];
  __syncthreads();

  float creg[7];
#pragma unroll
  for (int r = 0; r < 7; ++r) {
    int e = tid + 512 * r;
    if (e < 16 * H_N) {
      int m = e / H_N, j = e - m * H_N;
      int s = sId[m];
      float h = h0w[(size_t)s * H_N + j];
      u16 hh = f2bf(h);
      sHi[m * KP + j] = hh;
      sLo[m * KP + j] = f2bf(h - bf2f(hh));
      creg[r] = c0w[(size_t)s * H_N + j];
    }
  }
  __syncthreads();
  int Lmax = 1;
  for (int m = 0; m < 16; ++m) Lmax = max(Lmax, sLen[m]);

  const int lane = tid & 63;
  const int wv = tid >> 6;
  const int quad = lane >> 4;
  const int col = lane & 15;
  const int hpass = quad >> 1;

  const u16* aXh = sXhi + col * KP + quad * 8;
  const u16* aXl = sXlo + col * KP + quad * 8;
  const u16* aHh = sHi  + col * KP + quad * 8;
  const u16* aHl = sLo  + col * KP + quad * 8;

#pragma unroll 1
  for (int t = 0; t < Lmax; ++t) {
    for (int e = tid; e < 16 * H_N; e += 512) {
      int m = e / H_N, k = e - m * H_N;
      float v = words[((size_t)sId[m] * W_N + t) * H_N + k];
      u16 vh = f2bf(v);
      sXhi[m * KP + k] = vh;
      sXlo[m * KP + k] = f2bf(v - bf2f(vh));
    }
    __syncthreads();

    f32x4 acc[7];
#pragma unroll
    for (int i = 0; i < 7; ++i) { f32x4 z4 = {0.f, 0.f, 0.f, 0.f}; acc[i] = z4; }

#pragma unroll
    for (int kcc = 0; kcc < 7; ++kcc) {
      bf16x8 axh = *(const bf16x8*)(aXh + kcc * 32);
      bf16x8 axl = *(const bf16x8*)(aXl + kcc * 32);
      bf16x8 ahh = *(const bf16x8*)(aHh + kcc * 32);
      bf16x8 ahl = *(const bf16x8*)(aHl + kcc * 32);
#pragma unroll
      for (int i = 0; i < 7; ++i) {
        if (wv + 8 * i < 50) {
          bf16x8 bw = *pkptr(wih, wv + 8 * i, kcc, lane);
          bf16x8 bh = *pkptr(whh, wv + 8 * i, kcc, lane);
          acc[i] = __builtin_amdgcn_mfma_f32_16x16x32_bf16(axh, bw, acc[i], 0, 0, 0);
          acc[i] = __builtin_amdgcn_mfma_f32_16x16x32_bf16(axl, bw, acc[i], 0, 0, 0);
          acc[i] = __builtin_amdgcn_mfma_f32_16x16x32_bf16(ahh, bh, acc[i], 0, 0, 0);
          acc[i] = __builtin_amdgcn_mfma_f32_16x16x32_bf16(ahl, bh, acc[i], 0, 0, 0);
        }
      }
    }

#pragma unroll 1
    for (int h = 0; h < 2; ++h) {
      if (hpass == h) {
#pragma unroll
        for (int i = 0; i < 7; ++i) {
          int tt = wv + 8 * i;
          if (tt < 50) {
#pragma unroll
            for (int r = 0; r < 4; ++r)
              sG[((quad & 1) * 4 + r) * SGP + tt * 16 + col] = acc[i][r];
          }
        }
      }
      __syncthreads();
#pragma unroll
      for (int rr = 0; rr < 7; ++rr) {
        int e = tid + 512 * rr;
        if (e < 16 * H_N) {
          int m = e / H_N, j = e - m * H_N;
          if ((m >> 3) == h) {
            const float* gRow = sG + (m - 8 * h) * SGP;
            float ig = gRow[j] + sB[j];
            float fg = gRow[H_N + j] + sB[H_N + j];
            float gg = gRow[2 * H_N + j] + sB[2 * H_N + j];
            float og = gRow[3 * H_N + j] + sB[3 * H_N + j];
            float nc = fsigm(fg) * creg[rr] + fsigm(ig) * ftanh(gg);
            float nh = fsigm(og) * ftanh(nc);
            creg[rr] = nc;
            u16 hh = f2bf(nh);
            sHi[m * KP + j] = hh;
            sLo[m * KP + j] = f2bf(nh - bf2f(hh));
            if (t == sLen[m] - 1) {
              int s = sId[m];
              if (is_tgt) {
                if (m == 0) emb[(size_t)MID * H_N + j] = nh;
              } else if (s != MID) {
                emb[(size_t)s * H_N + j] = nh;
              }
            }
          }
        }
      }
      __syncthreads();
    }
  }
}

// ---------------------------------------------------------------------------
// Kernel 2: gx projections for prev/post via MFMA (packed wih).
// ---------------------------------------------------------------------------
__global__ __launch_bounds__(512) void k_gx(
    const float* __restrict__ emb,
    const u16* __restrict__ wihb_prev, const float* __restrict__ bih_prev, const float* __restrict__ bhh_prev,
    const u16* __restrict__ wihb_post, const float* __restrict__ bih_post, const float* __restrict__ bhh_post,
    float* __restrict__ gxp, float* __restrict__ gxq)
{
  const int tid = threadIdx.x;
  const int b = blockIdx.x;
  const bool post = (b >= 33);
  const int t0 = (post ? b - 33 : b) * 16;
  const u16* wih = post ? wihb_post : wihb_prev;
  const float* bih = post ? bih_post : bih_prev;
  const float* bhh = post ? bhh_post : bhh_prev;
  float* out = post ? gxq : gxp;

  __shared__ __align__(16) u16 sEhi[16 * KP];
  __shared__ __align__(16) u16 sElo[16 * KP];
  for (int e = tid; e < 16 * KP; e += 512) { sEhi[e] = 0; sElo[e] = 0; }
  __syncthreads();
  for (int e = tid; e < 16 * H_N; e += 512) {
    int m = e / H_N, k = e - m * H_N;
    int t = t0 + m;
    if (t <= 512) {
      int src = post ? (1024 - t) : t;
      float v = emb[(size_t)src * H_N + k];
      u16 vh = f2bf(v);
      sEhi[m * KP + k] = vh;
      sElo[m * KP + k] = f2bf(v - bf2f(vh));
    }
  }
  __syncthreads();

  const int lane = tid & 63;
  const int wv = tid >> 6;
  const int quad = lane >> 4;
  const int col = lane & 15;
  const u16* aH = sEhi + col * KP + quad * 8;
  const u16* aL = sElo + col * KP + quad * 8;

#pragma unroll 1
  for (int i = 0; i < 7; ++i) {
    int tt = wv + 8 * i;
    if (tt >= 50) break;
    int gate = tt * 16 + col;
    f32x4 acc = {0.f, 0.f, 0.f, 0.f};
#pragma unroll
    for (int kcc = 0; kcc < 7; ++kcc) {
      bf16x8 Ah = *(const bf16x8*)(aH + kcc * 32);
      bf16x8 Al = *(const bf16x8*)(aL + kcc * 32);
      bf16x8 bw = *pkptr(wih, tt, kcc, lane);
      acc = __builtin_amdgcn_mfma_f32_16x16x32_bf16(Ah, bw, acc, 0, 0, 0);
      acc = __builtin_amdgcn_mfma_f32_16x16x32_bf16(Al, bw, acc, 0, 0, 0);
    }
    float bias = bih[gate] + bhh[gate];
#pragma unroll
    for (int r = 0; r < 4; ++r) {
      int t = t0 + quad * 4 + r;
      if (t <= 512) out[(size_t)t * FH_N + gate] = acc[r] + bias;
    }
  }
}

// ---------------------------------------------------------------------------
// Kernel 3: prev/post sentence LSTMs, 513 serial steps. afr in regs/AGPRs;
// gx register-prefetched one step ahead; pad tiles skipped.
// ---------------------------------------------------------------------------
__global__ __launch_bounds__(512, 1) void k_sent(
    const u16* __restrict__ whhb_prev, const u16* __restrict__ whhb_post,
    const float* __restrict__ h0p, const float* __restrict__ c0p,
    const float* __restrict__ h0q, const float* __restrict__ c0q,
    const float* __restrict__ gxp, const float* __restrict__ gxq,
    float* __restrict__ outp, float* __restrict__ outq)
{
  const int tid = threadIdx.x;
  const bool post = (blockIdx.x != 0);
  const u16* whh = post ? whhb_post : whhb_prev;
  const float* h0 = post ? h0q : h0p;
  const float* c0 = post ? c0q : c0p;
  const float* gx = post ? gxq : gxp;
  float* outv = post ? outq : outp;

  __shared__ __align__(16) u16 sHi[224];
  __shared__ __align__(16) u16 sLo[224];
  __shared__ float sGa[FH_N];
  __shared__ float sGb[FH_N];

  const int lane = tid & 63;
  const int wv = tid >> 6;
  const int quad = lane >> 4;
  const int col = lane & 15;

  bf16x8 afr[7][7];
#pragma unroll
  for (int i = 0; i < 7; ++i)
#pragma unroll
    for (int kcc = 0; kcc < 7; ++kcc)
      afr[i][kcc] = *pkptr(whh, wv + 8 * i, kcc, lane);

  if (tid < 224) { sHi[tid] = 0; sLo[tid] = 0; }
  float c = 0.f, last_h = 0.f;
  if (tid < H_N) {
    float h = h0[tid];
    u16 hh = f2bf(h);
    sHi[tid] = hh;
    sLo[tid] = f2bf(h - bf2f(hh));
    c = c0[tid];
  }
  __syncthreads();

  const u16* hb = ((lane & 8) ? sLo : sHi) + quad * 8;
  const bool wrA = (col == 0), wrB = (col == 8);

  float gc0 = 0.f, gc1 = 0.f, gc2 = 0.f, gc3 = 0.f;
  if (tid < H_N) {
    gc0 = gx[tid]; gc1 = gx[H_N + tid]; gc2 = gx[2 * H_N + tid]; gc3 = gx[3 * H_N + tid];
  }

#pragma unroll 1
  for (int t = 0; t < 513; ++t) {
    bf16x8 bfr[7];
#pragma unroll
    for (int kcc = 0; kcc < 7; ++kcc) bfr[kcc] = *(const bf16x8*)(hb + kcc * 32);

    // prefetch next step's gx; completes during the MFMA phase
    float gn0 = 0.f, gn1 = 0.f, gn2 = 0.f, gn3 = 0.f;
    if (t + 1 < 513 && tid < H_N) {
      const float* g = gx + (size_t)(t + 1) * FH_N;
      gn0 = g[tid]; gn1 = g[H_N + tid]; gn2 = g[2 * H_N + tid]; gn3 = g[3 * H_N + tid];
    }

#pragma unroll
    for (int i = 0; i < 7; ++i) {
      int tt = wv + 8 * i;
      if (tt < 50) {                    // wave-uniform: skip pad tiles
        f32x4 acc = {0.f, 0.f, 0.f, 0.f};
#pragma unroll
        for (int kcc = 0; kcc < 7; ++kcc)
          acc = __builtin_amdgcn_mfma_f32_16x16x32_bf16(afr[i][kcc], bfr[kcc], acc, 0, 0, 0);
        if (wrA) {
#pragma unroll
          for (int r = 0; r < 4; ++r) sGa[tt * 16 + quad * 4 + r] = acc[r];
        } else if (wrB) {
#pragma unroll
          for (int r = 0; r < 4; ++r) sGb[tt * 16 + quad * 4 + r] = acc[r];
        }
      }
    }
    __syncthreads();

    if (tid < H_N) {
      float ig = sGa[tid] + sGb[tid] + gc0;
      float fg = sGa[H_N + tid] + sGb[H_N + tid] + gc1;
      float gg = sGa[2 * H_N + tid] + sGb[2 * H_N + tid] + gc2;
      float og = sGa[3 * H_N + tid] + sGb[3 * H_N + tid] + gc3;
      float nc = fsigm(fg) * c + fsigm(ig) * ftanh(gg);
      float nh = fsigm(og) * ftanh(nc);
      c = nc;
      last_h = nh;
      u16 hh = f2bf(nh);
      sHi[tid] = hh;
      sLo[tid] = f2bf(nh - bf2f(hh));
    }
    gc0 = gn0; gc1 = gn1; gc2 = gn2; gc3 = gn3;
    __syncthreads();
  }
  if (tid < H_N) outv[tid] = last_h;
}

// ---------------------------------------------------------------------------
// Kernel 4: out = [prev_out ; post_out] @ fc_w^T + fc_b
// ---------------------------------------------------------------------------
__global__ __launch_bounds__(256) void k_fc(
    const float* __restrict__ pout, const float* __restrict__ qout,
    const float* __restrict__ fc_w, const float* __restrict__ fc_b,
    float* __restrict__ out)
{
  const int tid = threadIdx.x;
  if (tid < H_N) {
    float d = fc_b[tid];
    const float* wr = fc_w + (size_t)tid * 2 * H_N;
    for (int k = 0; k < H_N; ++k) d += pout[k] * wr[k];
    for (int k = 0; k < H_N; ++k) d += qout[k] * wr[H_N + k];
    out[tid] = d;
  }
}

extern "C" void kernel_launch(void* const* d_in, const int* in_sizes, int n_in,
                              void* d_out, int out_size, void* d_ws, size_t ws_size,
                              hipStream_t stream) {
  const float* words   = (const float*)d_in[0];
  const int*   lengths = (const int*)d_in[1];
  const float* h0w = (const float*)d_in[2];
  const float* c0w = (const float*)d_in[3];
  const float* h0p = (const float*)d_in[4];
  const float* c0p = (const float*)d_in[5];
  const float* h0q = (const float*)d_in[6];
  const float* c0q = (const float*)d_in[7];
  const float* wih_ctx = (const float*)d_in[8];
  const float* whh_ctx = (const float*)d_in[9];
  const float* bih_ctx = (const float*)d_in[10];
  const float* bhh_ctx = (const float*)d_in[11];
  const float* wih_tgt = (const float*)d_in[12];
  const float* whh_tgt = (const float*)d_in[13];
  const float* bih_tgt = (const float*)d_in[14];
  const float* bhh_tgt = (const float*)d_in[15];
  const float* wih_prev = (const float*)d_in[16];
  const float* whh_prev = (const float*)d_in[17];
  const float* bih_prev = (const float*)d_in[18];
  const float* bhh_prev = (const float*)d_in[19];
  const float* wih_post = (const float*)d_in[20];
  const float* whh_post = (const float*)d_in[21];
  const float* bih_post = (const float*)d_in[22];
  const float* bhh_post = (const float*)d_in[23];
  const float* fc_w = (const float*)d_in[24];
  const float* fc_b = (const float*)d_in[25];
  (void)in_sizes; (void)n_in; (void)out_size;

  const size_t FIXF = 1448600;
  int CH = 0;
  for (int cand = 32; cand >= 1; cand >>= 1) {
    size_t needB = ((size_t)1026 * cand * 800 + FIXF) * 4 + 1056 * 4 + (size_t)8 * PKT * 2 + 256;
    if (ws_size >= needB) { CH = cand; break; }
  }

  float* ws = (float*)d_ws;
  float *gxc, *stateH, *stateC, *emb, *gxp, *gxq, *po, *qo;
  int* order;
  u16* wb;
  if (CH > 0) {
    gxc = ws;
    stateH = gxc + (size_t)1026 * CH * 800;
    stateC = stateH + 211200;
    emb = stateC + 211200;
    gxp = emb + 205000;
    gxq = gxp + 410400;
    po = gxq + 410400;
    qo = po + 200;
    order = (int*)(qo + 200);
    wb = (u16*)(order + 1056);
  } else {
    gxc = nullptr; stateH = nullptr; stateC = nullptr;
    emb = ws;
    gxp = ws + 205000;
    gxq = ws + 615400;
    po = ws + 1025800;
    qo = ws + 1026000;
    order = (int*)(ws + 1026200);
    wb = (u16*)(ws + 1027232);
  }
  u16* wihb_ctx  = wb;
  u16* whhb_ctx  = wb + PKT;
  u16* wihb_tgt  = wb + 2 * PKT;
  u16* whhb_tgt  = wb + 3 * PKT;
  u16* whhb_prev = wb + 4 * PKT;
  u16* whhb_post = wb + 5 * PKT;
  u16* wihb_prev = wb + 6 * PKT;
  u16* wihb_post = wb + 7 * PKT;

  k_w2b<<<(8 * PKT + 255) / 256, 256, 0, stream>>>(
      wih_ctx, whh_ctx, wih_tgt, whh_tgt, whh_prev, whh_post,
      wih_prev, wih_post, wb);
  k_sort<<<1, 1024, 0, stream>>>(lengths, order);

  if (CH > 0) {
    const int TT = (CH + 15) / 16;
    const int NC = (W_N + CH - 1) / CH;
    for (int c = 0; c < NC; ++c) {
      k_xpack<<<1026 * TT, 512, 0, stream>>>(c, CH, words, lengths,
                                             wihb_ctx, bih_ctx, bhh_ctx,
                                             wihb_tgt, bih_tgt, bhh_tgt, gxc);
      k_wrec<<<66, 512, 0, stream>>>(c, CH, lengths, order, h0w, c0w,
                                     whhb_ctx, whhb_tgt, gxc, stateH, stateC, emb);
    }
  } else {
    k_word_s<<<66, 512, 0, stream>>>(words, lengths, order, h0w, c0w,
                                     wihb_ctx, whhb_ctx, bih_ctx, bhh_ctx,
                                     wihb_tgt, whhb_tgt, bih_tgt, bhh_tgt, emb);
  }
  k_gx<<<66, 512, 0, stream>>>(emb, wihb_prev, bih_prev, bhh_prev,
                               wihb_post, bih_post, bhh_post, gxp, gxq);
  k_sent<<<2, 512, 0, stream>>>(whhb_prev, whhb_post, h0p, c0p, h0q, c0q,
                                gxp, gxq, po, qo);
  k_fc<<<1, 256, 0, stream>>>(po, qo, fc_w, fc_b, (float*)d_out);
}